// Round 8
// baseline (2136.825 us; speedup 1.0000x reference)
//
#include <hip/hip_runtime.h>

typedef __attribute__((ext_vector_type(4))) float f32x4;
typedef __attribute__((ext_vector_type(8))) short bf16x8;

#define B_   128
#define T_   1024
#define NROW 131072      // B*T
#define HB   (NROW*300)  // floats in the [B*T][300] matrix
#define NL2E -1.44269504088896340736f   // -log2(e)

__device__ inline unsigned short f2bf(float f) {
    union { float f; unsigned int u; } v; v.f = f;
    unsigned int r = v.u + 0x7FFFu + ((v.u >> 16) & 1u);
    return (unsigned short)(r >> 16);
}

// Load up to 8 consecutive f32 (zero-masked at K=300 boundary), scale, convert
// to bf16, return packed uint4 (8 bf16, fragment j-order = ascending k).
__device__ inline uint4 load8_cvt_s(const float* src, bool rowok, int krem, float scale) {
    f32x4 v0 = {0.f,0.f,0.f,0.f}, v1 = {0.f,0.f,0.f,0.f};
    if (rowok) {
        if (krem >= 8)      { v0 = *(const f32x4*)src; v1 = *(const f32x4*)(src + 4); }
        else if (krem >= 4) { v0 = *(const f32x4*)src; }
    }
    v0 *= scale; v1 *= scale;
    uint4 p;
    p.x = (unsigned)f2bf(v0[0]) | ((unsigned)f2bf(v0[1]) << 16);
    p.y = (unsigned)f2bf(v0[2]) | ((unsigned)f2bf(v0[3]) << 16);
    p.z = (unsigned)f2bf(v1[0]) | ((unsigned)f2bf(v1[1]) << 16);
    p.w = (unsigned)f2bf(v1[2]) | ((unsigned)f2bf(v1[3]) << 16);
    return p;
}

__device__ inline uint4 load8_cvt(const float* src, bool rowok, int krem) {
    return load8_cvt_s(src, rowok, krem, 1.0f);
}

// ---------------------------------------------------------------------------
// K1: A[m][n] = -log2e * (sum_k X[m][k]*W1[n][k] + b1[n])   (bf16 MFMA)
// ---------------------------------------------------------------------------
__global__ __launch_bounds__(256) void gemm_in(
    const float* __restrict__ X, const float* __restrict__ W1,
    const float* __restrict__ b1, float* __restrict__ A)
{
    __shared__ unsigned short alds[8 * 64 * 8];
    __shared__ unsigned short blds[10 * 64 * 8];
    const int tid = threadIdx.x;
    const int w = tid >> 6, l = tid & 63, lg = l >> 4, ln = l & 15;
    const size_t m0 = (size_t)blockIdx.x * 128;
    const int n0 = blockIdx.y * 160;

    f32x4 acc[2][10];
    #pragma unroll
    for (int q = 0; q < 2; ++q)
        #pragma unroll
        for (int nt = 0; nt < 10; ++nt) acc[q][nt] = (f32x4){0.f,0.f,0.f,0.f};

    for (int kt = 0; kt < 10; ++kt) {
        const int kc = kt * 32;
        __syncthreads();
        #pragma unroll
        for (int rep = 0; rep < 2; ++rep) {
            int e = tid + rep * 256;
            int row = e >> 2, kh = e & 3;
            int k0 = kc + kh * 8;
            uint4 p = load8_cvt(X + (m0 + row) * 300 + k0, true, 300 - k0);
            *(uint4*)&alds[(((row >> 4) * 64) + kh * 16 + (row & 15)) * 8] = p;
        }
        #pragma unroll
        for (int rep = 0; rep < 3; ++rep) {
            int e = tid + rep * 256;
            if (e < 640) {
                int nn = e >> 2, kh = e & 3;
                int n = n0 + nn;
                int k0 = kc + kh * 8;
                uint4 p = load8_cvt(W1 + (size_t)n * 600 + k0, n < 300, 300 - k0);
                *(uint4*)&blds[(((nn >> 4) * 64) + kh * 16 + (nn & 15)) * 8] = p;
            }
        }
        __syncthreads();
        bf16x8 bfr[10];
        #pragma unroll
        for (int nt = 0; nt < 10; ++nt) bfr[nt] = *(const bf16x8*)&blds[(nt * 64 + l) * 8];
        #pragma unroll
        for (int q = 0; q < 2; ++q) {
            bf16x8 afr = *(const bf16x8*)&alds[((w * 2 + q) * 64 + l) * 8];
            #pragma unroll
            for (int nt = 0; nt < 10; ++nt)
                acc[q][nt] = __builtin_amdgcn_mfma_f32_16x16x32_bf16(afr, bfr[nt], acc[q][nt], 0, 0, 0);
        }
    }

    #pragma unroll
    for (int q = 0; q < 2; ++q)
        #pragma unroll
        for (int nt = 0; nt < 10; ++nt) {
            int n = n0 + nt * 16 + ln;
            if (n < 300) {
                float bias = b1[n];
                size_t mr = m0 + (w * 2 + q) * 16 + lg * 4;
                #pragma unroll
                for (int i = 0; i < 4; ++i)
                    A[(mr + i) * 300 + n] = (acc[q][nt][i] + bias) * NL2E;
            }
        }
}

// ---------------------------------------------------------------------------
// K2: recurrence. 8 blocks x 256 thr (4 waves, 1/SIMD). Each wave owns 5
// M-tiles (afrag[5][10] in unified VGPR/AGPR file). h via double-buffered LDS
// B-frags — broadcast cost halved vs 8-wave (40 ds_read_b128/step/CU). One raw
// s_barrier + lgkmcnt(0) per step; globals stay in flight. A' folded into MFMA
// C-init. Sigmoid = v_exp_f32 + add + v_rcp_f32. Race-free delayed stores:
// stores at step t cover times <= t-1; prefetch reads t+2.
// ---------------------------------------------------------------------------
#define K2_STEP(P, tval, ASLOT, HPME, HPOTHER)                                  \
    {                                                                           \
        const int t = (tval);                                                   \
        if (t > 0) {                                                            \
            const int tt = t - 1;                                               \
            const size_t so = (size_t)(tt >> 6) * 76800 + (size_t)(tt & 63) * 600; \
            _Pragma("unroll")                                                   \
            for (int q = 0; q < 5; ++q)                                         \
                if (rq[q] < 300)                                                \
                    *(uint2*)(sbase + so + rq[q] * 2) = HPOTHER[q];             \
        }                                                                       \
        bf16x8 bfr[10];                                                         \
        _Pragma("unroll")                                                       \
        for (int kt = 0; kt < 10; ++kt)                                         \
            bfr[kt] = *(const bf16x8*)&hlds[P][(kt * 64 + l) * 8];              \
        f32x4 acc[5], accB[5];                                                  \
        _Pragma("unroll")                                                       \
        for (int q = 0; q < 5; ++q) {                                           \
            acc[q] = ASLOT[q];                                                  \
            accB[q] = (f32x4){0.f,0.f,0.f,0.f};                                 \
        }                                                                       \
        _Pragma("unroll")                                                       \
        for (int kt = 0; kt < 5; ++kt) {                                        \
            _Pragma("unroll")                                                   \
            for (int q = 0; q < 5; ++q) {                                       \
                acc[q]  = __builtin_amdgcn_mfma_f32_16x16x32_bf16(afrag[q][kt],   bfr[kt],   acc[q],  0, 0, 0); \
                accB[q] = __builtin_amdgcn_mfma_f32_16x16x32_bf16(afrag[q][kt+5], bfr[kt+5], accB[q], 0, 0, 0); \
            }                                                                   \
        }                                                                       \
        _Pragma("unroll")                                                       \
        for (int q = 0; q < 5; ++q) {                                           \
            f32x4 hv;                                                           \
            _Pragma("unroll")                                                   \
            for (int i = 0; i < 4; ++i) {                                       \
                float zn = acc[q][i] + accB[q][i];      /* = -z*log2e */        \
                float ex, sg;                                                   \
                asm("v_exp_f32 %0, %1" : "=v"(ex) : "v"(zn));                   \
                asm("v_rcp_f32 %0, %1" : "=v"(sg) : "v"(1.0f + ex));            \
                hv[i] = sg;                                                     \
            }                                                                   \
            unsigned plo, phi;                                                  \
            asm("v_cvt_pk_bf16_f32 %0, %1, %2" : "=v"(plo) : "v"(hv[0]), "v"(hv[1])); \
            asm("v_cvt_pk_bf16_f32 %0, %1, %2" : "=v"(phi) : "v"(hv[2]), "v"(hv[3])); \
            HPME[q].x = plo; HPME[q].y = phi;                                   \
            *(uint2*)((char*)hlds + ((P) ^ 1) * 10240 + ldsoff[q]) = HPME[q];   \
            if (t == T_ - 1 && rq[q] < 300)                                     \
                *(f32x4*)(hfinal + bb * 300 + rq[q]) = hv;                      \
        }                                                                       \
        if (t < T_ - 2) {                                                       \
            const char* ar = abase + (size_t)(t + 2) * 1200;                    \
            _Pragma("unroll")                                                   \
            for (int q = 0; q < 5; ++q)                                         \
                ASLOT[q] = *(const f32x4*)(ar + rq[q] * 4);                     \
        }                                                                       \
        asm volatile("s_waitcnt lgkmcnt(0)" ::: "memory");                      \
        __builtin_amdgcn_s_barrier();                                           \
        asm volatile("" ::: "memory");                                          \
    }

__global__ __launch_bounds__(256, 1) void elman_rec_mfma(
    const float* __restrict__ W1, float* __restrict__ buf,
    float* __restrict__ hfinal)
{
    __shared__ unsigned short hlds[2][10 * 64 * 8];   // 2 x 10240 B
    const int tid = threadIdx.x;
    const int w = tid >> 6, l = tid & 63, lg = l >> 4, ln = l & 15;
    const int bb = blockIdx.x * 16 + ln;    // this lane's batch (B/C column)

    int rq[5], ldsoff[5];
    #pragma unroll
    for (int q = 0; q < 5; ++q) {
        int tile = w * 5 + q;
        int r = tile * 16 + 4 * lg;
        rq[q] = r;
        ldsoff[q] = (((r >> 5) * 64 + ((r >> 3) & 3) * 16 + ln) * 8 + (r & 7)) * 2;
    }

    // W1h A-fragments, scaled by -log2e (rows >=300, k>=300 zeroed)
    bf16x8 afrag[5][10];
    #pragma unroll
    for (int q = 0; q < 5; ++q) {
        #pragma unroll
        for (int kt = 0; kt < 10; ++kt) {
            int tile = w * 5 + q;
            int r = tile * 16 + ln;
            int k0 = kt * 32 + lg * 8;
            uint4 p = load8_cvt_s(W1 + (size_t)r * 600 + 300 + k0,
                                  r < 300, 300 - k0, NL2E);
            union { uint4 u; bf16x8 s; } cv; cv.u = p;
            afrag[q][kt] = cv.s;
        }
    }

    for (int i = tid; i < 10 * 64 * 8; i += 256) hlds[0][i] = 0;

    // per-lane base pointers
    const char* abase = (const char*)(buf + (size_t)bb * T_ * 300);
    char* sbase = (char*)buf + (size_t)bb * 16 * 76800;

    // prefetch A'(0) -> slot0, A'(1) -> slot1
    // (rows >=300 read harmless in-buffer garbage; results discarded via zero
    //  afrag k-columns and rq<300 store guards; bytes stay inside d_out.)
    f32x4 A0[5], A1[5];
    #pragma unroll
    for (int q = 0; q < 5; ++q) {
        A0[q] = *(const f32x4*)(abase + rq[q] * 4);
        A1[q] = *(const f32x4*)(abase + 1200 + rq[q] * 4);
    }
    uint2 hpA[5], hpB[5];
    __syncthreads();

    for (int t2 = 0; t2 < T_; t2 += 2) {
        K2_STEP(0, t2,     A0, hpA, hpB)
        K2_STEP(1, t2 + 1, A1, hpB, hpA)
    }

    // tail: packed store for t=1023 (parity 1 -> hpB)
    {
        const int tt = T_ - 1;
        const size_t so = (size_t)(tt >> 6) * 76800 + (size_t)(tt & 63) * 600;
        #pragma unroll
        for (int q = 0; q < 5; ++q)
            if (rq[q] < 300)
                *(uint2*)(sbase + so + rq[q] * 2) = hpB[q];
    }
}

// ---------------------------------------------------------------------------
// K3: out[m][n] = sum_k h[m][k]*W2[n][k] + b2[n], in place over packed-h buf.
// One block per 64-row chunk (grid 2048); block computes ALL 300 columns.
// ---------------------------------------------------------------------------
__global__ __launch_bounds__(256) void gemm_out(
    float* __restrict__ buf, const float* __restrict__ W2,
    const float* __restrict__ b2)
{
    __shared__ unsigned short alds[4 * 64 * 8];
    __shared__ unsigned short blds[19 * 64 * 8];
    const int tid = threadIdx.x;
    const int w = tid >> 6, l = tid & 63, lg = l >> 4, ln = l & 15;
    const size_t chunk = blockIdx.x;
    const char* pbase = (const char*)buf + chunk * 76800;

    f32x4 acc[19];
    #pragma unroll
    for (int nt = 0; nt < 19; ++nt) acc[nt] = (f32x4){0.f,0.f,0.f,0.f};

    for (int kt = 0; kt < 10; ++kt) {
        const int kc = kt * 32;
        __syncthreads();
        {
            int row = tid >> 2, kh = tid & 3;
            int k0 = kc + kh * 8;
            const char* p = pbase + row * 600;
            uint2 lo = make_uint2(0u, 0u), hi = make_uint2(0u, 0u);
            int krem = 300 - k0;
            if (krem >= 8)      { lo = *(const uint2*)(p + k0 * 2); hi = *(const uint2*)(p + k0 * 2 + 8); }
            else if (krem >= 4) { lo = *(const uint2*)(p + k0 * 2); }
            uint4 pk; pk.x = lo.x; pk.y = lo.y; pk.z = hi.x; pk.w = hi.y;
            *(uint4*)&alds[(((row >> 4) * 64) + kh * 16 + (row & 15)) * 8] = pk;
        }
        #pragma unroll
        for (int rep = 0; rep < 5; ++rep) {
            int e = tid + rep * 256;
            if (e < 1216) {
                int nn = e >> 2, kh = e & 3;
                int k0 = kc + kh * 8;
                uint4 p = load8_cvt(W2 + (size_t)nn * 300 + k0, nn < 300, 300 - k0);
                *(uint4*)&blds[(((nn >> 4) * 64) + kh * 16 + (nn & 15)) * 8] = p;
            }
        }
        __syncthreads();
        bf16x8 afr = *(const bf16x8*)&alds[(w * 64 + l) * 8];
        #pragma unroll
        for (int nt = 0; nt < 19; ++nt) {
            bf16x8 bfr = *(const bf16x8*)&blds[(nt * 64 + l) * 8];
            acc[nt] = __builtin_amdgcn_mfma_f32_16x16x32_bf16(afr, bfr, acc[nt], 0, 0, 0);
        }
    }

    float* frow = buf + chunk * 19200;
    #pragma unroll
    for (int nt = 0; nt < 19; ++nt) {
        int n = nt * 16 + ln;
        if (n < 300) {
            float bias = b2[n];
            int mr = w * 16 + lg * 4;
            #pragma unroll
            for (int i = 0; i < 4; ++i)
                frow[(mr + i) * 300 + n] = acc[nt][i] + bias;
        }
    }
}

// ---------------------------------------------------------------------------
extern "C" void kernel_launch(void* const* d_in, const int* in_sizes, int n_in,
                              void* d_out, int out_size, void* d_ws, size_t ws_size,
                              hipStream_t stream)
{
    const float* x  = (const float*)d_in[0];
    const float* W1 = (const float*)d_in[1];
    const float* b1 = (const float*)d_in[2];
    const float* W2 = (const float*)d_in[3];
    const float* b2 = (const float*)d_in[4];

    float* out    = (float*)d_out;
    float* hfinal = out + (size_t)HB;

    gemm_in<<<dim3(1024, 2), 256, 0, stream>>>(x, W1, b1, out);
    elman_rec_mfma<<<8, 256, 0, stream>>>(W1, out, hfinal);
    gemm_out<<<2048, 256, 0, stream>>>(out, W2, b2);
}

// Round 9
// 1723.431 us; speedup vs baseline: 1.2399x; 1.2399x over previous
//
#include <hip/hip_runtime.h>

typedef __attribute__((ext_vector_type(4))) float f32x4;
typedef __attribute__((ext_vector_type(8))) short bf16x8;

#define B_   128
#define T_   1024
#define NROW 131072      // B*T
#define HB   (NROW*300)  // floats in the [B*T][300] matrix
#define NL2E -1.44269504088896340736f   // -log2(e)

__device__ inline unsigned short f2bf(float f) {
    union { float f; unsigned int u; } v; v.f = f;
    unsigned int r = v.u + 0x7FFFu + ((v.u >> 16) & 1u);
    return (unsigned short)(r >> 16);
}

// Load up to 8 consecutive f32 (zero-masked at K=300 boundary), scale, convert
// to bf16, return packed uint4 (8 bf16, fragment j-order = ascending k).
__device__ inline uint4 load8_cvt_s(const float* src, bool rowok, int krem, float scale) {
    f32x4 v0 = {0.f,0.f,0.f,0.f}, v1 = {0.f,0.f,0.f,0.f};
    if (rowok) {
        if (krem >= 8)      { v0 = *(const f32x4*)src; v1 = *(const f32x4*)(src + 4); }
        else if (krem >= 4) { v0 = *(const f32x4*)src; }
    }
    v0 *= scale; v1 *= scale;
    uint4 p;
    p.x = (unsigned)f2bf(v0[0]) | ((unsigned)f2bf(v0[1]) << 16);
    p.y = (unsigned)f2bf(v0[2]) | ((unsigned)f2bf(v0[3]) << 16);
    p.z = (unsigned)f2bf(v1[0]) | ((unsigned)f2bf(v1[1]) << 16);
    p.w = (unsigned)f2bf(v1[2]) | ((unsigned)f2bf(v1[3]) << 16);
    return p;
}

__device__ inline uint4 load8_cvt(const float* src, bool rowok, int krem) {
    return load8_cvt_s(src, rowok, krem, 1.0f);
}

// ---------------------------------------------------------------------------
// K1: A[m][n] = -log2e * (sum_k X[m][k]*W1[n][k] + b1[n])   (bf16 MFMA)
// ---------------------------------------------------------------------------
__global__ __launch_bounds__(256) void gemm_in(
    const float* __restrict__ X, const float* __restrict__ W1,
    const float* __restrict__ b1, float* __restrict__ A)
{
    __shared__ unsigned short alds[8 * 64 * 8];
    __shared__ unsigned short blds[10 * 64 * 8];
    const int tid = threadIdx.x;
    const int w = tid >> 6, l = tid & 63, lg = l >> 4, ln = l & 15;
    const size_t m0 = (size_t)blockIdx.x * 128;
    const int n0 = blockIdx.y * 160;

    f32x4 acc[2][10];
    #pragma unroll
    for (int q = 0; q < 2; ++q)
        #pragma unroll
        for (int nt = 0; nt < 10; ++nt) acc[q][nt] = (f32x4){0.f,0.f,0.f,0.f};

    for (int kt = 0; kt < 10; ++kt) {
        const int kc = kt * 32;
        __syncthreads();
        #pragma unroll
        for (int rep = 0; rep < 2; ++rep) {
            int e = tid + rep * 256;
            int row = e >> 2, kh = e & 3;
            int k0 = kc + kh * 8;
            uint4 p = load8_cvt(X + (m0 + row) * 300 + k0, true, 300 - k0);
            *(uint4*)&alds[(((row >> 4) * 64) + kh * 16 + (row & 15)) * 8] = p;
        }
        #pragma unroll
        for (int rep = 0; rep < 3; ++rep) {
            int e = tid + rep * 256;
            if (e < 640) {
                int nn = e >> 2, kh = e & 3;
                int n = n0 + nn;
                int k0 = kc + kh * 8;
                uint4 p = load8_cvt(W1 + (size_t)n * 600 + k0, n < 300, 300 - k0);
                *(uint4*)&blds[(((nn >> 4) * 64) + kh * 16 + (nn & 15)) * 8] = p;
            }
        }
        __syncthreads();
        bf16x8 bfr[10];
        #pragma unroll
        for (int nt = 0; nt < 10; ++nt) bfr[nt] = *(const bf16x8*)&blds[(nt * 64 + l) * 8];
        #pragma unroll
        for (int q = 0; q < 2; ++q) {
            bf16x8 afr = *(const bf16x8*)&alds[((w * 2 + q) * 64 + l) * 8];
            #pragma unroll
            for (int nt = 0; nt < 10; ++nt)
                acc[q][nt] = __builtin_amdgcn_mfma_f32_16x16x32_bf16(afr, bfr[nt], acc[q][nt], 0, 0, 0);
        }
    }

    #pragma unroll
    for (int q = 0; q < 2; ++q)
        #pragma unroll
        for (int nt = 0; nt < 10; ++nt) {
            int n = n0 + nt * 16 + ln;
            if (n < 300) {
                float bias = b1[n];
                size_t mr = m0 + (w * 2 + q) * 16 + lg * 4;
                #pragma unroll
                for (int i = 0; i < 4; ++i)
                    A[(mr + i) * 300 + n] = (acc[q][nt][i] + bias) * NL2E;
            }
        }
}

// ---------------------------------------------------------------------------
// K2: recurrence. 8 blocks x 512 thr (8 waves, 2/SIMD — best measured TLP).
// W1h (bf16, -log2e-scaled) in A-frags; h via double-buffered LDS B-frags.
// Per-q epilogue interleave: sigmoid/ds_write/global-store issued per M-group
// right after its MFMA chains -> ds_writes drain early, stores off step head.
// A-prefetch issued early via linear running pointers (no addr recompute, no
// end guards: tail loads are in-bounds junk, discarded). setprio(1) around
// MFMA cluster. One lgkmcnt(0)+s_barrier per step; globals stay in flight.
// Race-free: packed h stores at step t cover times <= t-1; loads read t+2.
// ---------------------------------------------------------------------------
#define QOK(q) ((q) < 2 || w4)

#define K2_STEP(P, tval, ASLOT, APTR, HPME, HPOTHER)                            \
    {                                                                           \
        const int t = (tval);                                                   \
        const int tt = t - 1;                                                   \
        const size_t so = (size_t)(tt >> 6) * 76800 + (size_t)(tt & 63) * 600;  \
        bf16x8 bfr[10];                                                         \
        _Pragma("unroll")                                                       \
        for (int kt = 0; kt < 10; ++kt)                                         \
            bfr[kt] = *(const bf16x8*)&hlds[P][(kt * 64 + l) * 8];              \
        f32x4 acc[3], accB[3];                                                  \
        _Pragma("unroll")                                                       \
        for (int q = 0; q < 3; ++q) {                                           \
            acc[q] = QOK(q) ? ASLOT[q] : (f32x4){0.f,0.f,0.f,0.f};              \
            accB[q] = (f32x4){0.f,0.f,0.f,0.f};                                 \
        }                                                                       \
        /* early prefetch issue for t+2 (linear pointer, unguarded) */          \
        _Pragma("unroll")                                                       \
        for (int q = 0; q < 3; ++q)                                             \
            if (QOK(q)) ASLOT[q] = *(const f32x4*)(APTR + rq[q] * 4);           \
        APTR += 2400;                                                           \
        __builtin_amdgcn_s_setprio(1);                                          \
        _Pragma("unroll")                                                       \
        for (int kt = 0; kt < 5; ++kt) {                                        \
            acc[0]  = __builtin_amdgcn_mfma_f32_16x16x32_bf16(afrag[0][kt],   bfr[kt],   acc[0],  0, 0, 0); \
            accB[0] = __builtin_amdgcn_mfma_f32_16x16x32_bf16(afrag[0][kt+5], bfr[kt+5], accB[0], 0, 0, 0); \
            acc[1]  = __builtin_amdgcn_mfma_f32_16x16x32_bf16(afrag[1][kt],   bfr[kt],   acc[1],  0, 0, 0); \
            accB[1] = __builtin_amdgcn_mfma_f32_16x16x32_bf16(afrag[1][kt+5], bfr[kt+5], accB[1], 0, 0, 0); \
            if (w4) {                                                           \
                acc[2]  = __builtin_amdgcn_mfma_f32_16x16x32_bf16(afrag[2][kt],   bfr[kt],   acc[2],  0, 0, 0); \
                accB[2] = __builtin_amdgcn_mfma_f32_16x16x32_bf16(afrag[2][kt+5], bfr[kt+5], accB[2], 0, 0, 0); \
            }                                                                   \
        }                                                                       \
        __builtin_amdgcn_s_setprio(0);                                          \
        /* per-q epilogue: sigmoid -> pack -> ds_write -> delayed global store */ \
        _Pragma("unroll")                                                       \
        for (int q = 0; q < 3; ++q) {                                           \
            if (!QOK(q)) continue;                                              \
            f32x4 hv;                                                           \
            _Pragma("unroll")                                                   \
            for (int i = 0; i < 4; ++i) {                                       \
                float zn = acc[q][i] + accB[q][i];      /* = -z*log2e */        \
                float ex, sg;                                                   \
                asm("v_exp_f32 %0, %1" : "=v"(ex) : "v"(zn));                   \
                asm("v_rcp_f32 %0, %1" : "=v"(sg) : "v"(1.0f + ex));            \
                hv[i] = sg;                                                     \
            }                                                                   \
            unsigned plo, phi;                                                  \
            asm("v_cvt_pk_bf16_f32 %0, %1, %2" : "=v"(plo) : "v"(hv[0]), "v"(hv[1])); \
            asm("v_cvt_pk_bf16_f32 %0, %1, %2" : "=v"(phi) : "v"(hv[2]), "v"(hv[3])); \
            HPME[q].x = plo; HPME[q].y = phi;                                   \
            *(uint2*)((char*)hlds + ((P) ^ 1) * 10240 + ldsoff[q]) = HPME[q];   \
            if (t > 0 && rq[q] < 300)                                           \
                *(uint2*)(sbase + so + rq[q] * 2) = HPOTHER[q];                 \
        }                                                                       \
        asm volatile("s_waitcnt lgkmcnt(0)" ::: "memory");                      \
        __builtin_amdgcn_s_barrier();                                           \
        asm volatile("" ::: "memory");                                          \
    }

__global__ __launch_bounds__(512) void elman_rec_mfma(
    const float* __restrict__ W1, float* __restrict__ buf,
    float* __restrict__ hfinal)
{
    __shared__ unsigned short hlds[2][10 * 64 * 8];   // 2 x 10240 B
    const int tid = threadIdx.x;
    const int w = tid >> 6, l = tid & 63, lg = l >> 4, ln = l & 15;
    const bool w4 = (w < 4);
    const int bb = blockIdx.x * 16 + ln;    // this lane's batch (B/C column)

    int rq[3], ldsoff[3];
    #pragma unroll
    for (int q = 0; q < 3; ++q) {
        int tile = w4 ? (3 * w + q) : (12 + 2 * (w - 4) + q);
        int r = tile * 16 + 4 * lg;
        rq[q] = r;
        ldsoff[q] = (((r >> 5) * 64 + ((r >> 3) & 3) * 16 + ln) * 8 + (r & 7)) * 2;
    }

    // W1h A-fragments, scaled by -log2e (rows >=300, k>=300 zeroed)
    bf16x8 afrag[3][10];
    #pragma unroll
    for (int q = 0; q < 3; ++q) {
        #pragma unroll
        for (int kt = 0; kt < 10; ++kt) {
            bool qa = (q < 2) || w4;
            int tile = w4 ? (3 * w + q) : (12 + 2 * (w - 4) + q);
            int r = tile * 16 + ln;
            int k0 = kt * 32 + lg * 8;
            uint4 p = load8_cvt_s(W1 + (size_t)r * 600 + 300 + k0,
                                  qa && r < 300, 300 - k0, NL2E);
            union { uint4 u; bf16x8 s; } cv; cv.u = p;
            afrag[q][kt] = cv.s;
        }
    }

    for (int i = tid; i < 10 * 64 * 8; i += 512) hlds[0][i] = 0;

    // per-lane base pointers
    const char* abase = (const char*)(buf + (size_t)bb * T_ * 300);
    char* sbase = (char*)buf + (size_t)bb * 16 * 76800;

    // prefetch A'(0) -> slot0, A'(1) -> slot1
    f32x4 A0[3], A1[3];
    #pragma unroll
    for (int q = 0; q < 3; ++q)
        if (QOK(q)) {
            A0[q] = *(const f32x4*)(abase + rq[q] * 4);
            A1[q] = *(const f32x4*)(abase + 1200 + rq[q] * 4);
        }
    const char* aptr0 = abase + 2400;   // even steps load t+2
    const char* aptr1 = abase + 3600;   // odd steps load t+2
    uint2 hpA[3], hpB[3];
    __syncthreads();

    for (int t2 = 0; t2 < T_; t2 += 2) {
        K2_STEP(0, t2,     A0, aptr0, hpA, hpB)
        K2_STEP(1, t2 + 1, A1, aptr1, hpB, hpA)
    }

    // tail: packed store for t=1023 (parity 1 -> hpB), plus hfinal (unpacked)
    {
        const int tt = T_ - 1;
        const size_t so = (size_t)(tt >> 6) * 76800 + (size_t)(tt & 63) * 600;
        #pragma unroll
        for (int q = 0; q < 3; ++q)
            if (QOK(q) && rq[q] < 300) {
                *(uint2*)(sbase + so + rq[q] * 2) = hpB[q];
                f32x4 hv;
                union { float f; unsigned u; } c0, c1, c2, c3;
                c0.u = hpB[q].x << 16; c1.u = hpB[q].x & 0xFFFF0000u;
                c2.u = hpB[q].y << 16; c3.u = hpB[q].y & 0xFFFF0000u;
                hv[0] = c0.f; hv[1] = c1.f; hv[2] = c2.f; hv[3] = c3.f;
                *(f32x4*)(hfinal + bb * 300 + rq[q]) = hv;
            }
    }
}

// ---------------------------------------------------------------------------
// K3: out[m][n] = sum_k h[m][k]*W2[n][k] + b2[n], in place over packed-h buf.
// One block per 64-row chunk (grid 2048); block computes ALL 300 columns.
// ---------------------------------------------------------------------------
__global__ __launch_bounds__(256) void gemm_out(
    float* __restrict__ buf, const float* __restrict__ W2,
    const float* __restrict__ b2)
{
    __shared__ unsigned short alds[4 * 64 * 8];
    __shared__ unsigned short blds[19 * 64 * 8];
    const int tid = threadIdx.x;
    const int w = tid >> 6, l = tid & 63, lg = l >> 4, ln = l & 15;
    const size_t chunk = blockIdx.x;
    const char* pbase = (const char*)buf + chunk * 76800;

    f32x4 acc[19];
    #pragma unroll
    for (int nt = 0; nt < 19; ++nt) acc[nt] = (f32x4){0.f,0.f,0.f,0.f};

    for (int kt = 0; kt < 10; ++kt) {
        const int kc = kt * 32;
        __syncthreads();
        {
            int row = tid >> 2, kh = tid & 3;
            int k0 = kc + kh * 8;
            const char* p = pbase + row * 600;
            uint2 lo = make_uint2(0u, 0u), hi = make_uint2(0u, 0u);
            int krem = 300 - k0;
            if (krem >= 8)      { lo = *(const uint2*)(p + k0 * 2); hi = *(const uint2*)(p + k0 * 2 + 8); }
            else if (krem >= 4) { lo = *(const uint2*)(p + k0 * 2); }
            uint4 pk; pk.x = lo.x; pk.y = lo.y; pk.z = hi.x; pk.w = hi.y;
            *(uint4*)&alds[(((row >> 4) * 64) + kh * 16 + (row & 15)) * 8] = pk;
        }
        #pragma unroll
        for (int rep = 0; rep < 5; ++rep) {
            int e = tid + rep * 256;
            if (e < 1216) {
                int nn = e >> 2, kh = e & 3;
                int k0 = kc + kh * 8;
                uint4 p = load8_cvt(W2 + (size_t)nn * 300 + k0, nn < 300, 300 - k0);
                *(uint4*)&blds[(((nn >> 4) * 64) + kh * 16 + (nn & 15)) * 8] = p;
            }
        }
        __syncthreads();
        bf16x8 afr = *(const bf16x8*)&alds[(w * 64 + l) * 8];
        #pragma unroll
        for (int nt = 0; nt < 19; ++nt) {
            bf16x8 bfr = *(const bf16x8*)&blds[(nt * 64 + l) * 8];
            acc[nt] = __builtin_amdgcn_mfma_f32_16x16x32_bf16(afr, bfr, acc[nt], 0, 0, 0);
        }
    }

    float* frow = buf + chunk * 19200;
    #pragma unroll
    for (int nt = 0; nt < 19; ++nt) {
        int n = nt * 16 + ln;
        if (n < 300) {
            float bias = b2[n];
            int mr = w * 16 + lg * 4;
            #pragma unroll
            for (int i = 0; i < 4; ++i)
                frow[(mr + i) * 300 + n] = acc[nt][i] + bias;
        }
    }
}

// ---------------------------------------------------------------------------
extern "C" void kernel_launch(void* const* d_in, const int* in_sizes, int n_in,
                              void* d_out, int out_size, void* d_ws, size_t ws_size,
                              hipStream_t stream)
{
    const float* x  = (const float*)d_in[0];
    const float* W1 = (const float*)d_in[1];
    const float* b1 = (const float*)d_in[2];
    const float* W2 = (const float*)d_in[3];
    const float* b2 = (const float*)d_in[4];

    float* out    = (float*)d_out;
    float* hfinal = out + (size_t)HB;

    gemm_in<<<dim3(1024, 2), 256, 0, stream>>>(x, W1, b1, out);
    elman_rec_mfma<<<8, 512, 0, stream>>>(W1, out, hfinal);
    gemm_out<<<2048, 256, 0, stream>>>(out, W2, b2);
}

// Round 10
// 1336.967 us; speedup vs baseline: 1.5983x; 1.2891x over previous
//
#include <hip/hip_runtime.h>

typedef __attribute__((ext_vector_type(4))) float f32x4;
typedef __attribute__((ext_vector_type(8))) short bf16x8;

#define B_   128
#define T_   1024
#define NROW 131072      // B*T
#define HB   (NROW*300)  // floats in the [B*T][300] matrix
#define NL2E -1.44269504088896340736f   // -log2(e)

__device__ inline unsigned short f2bf(float f) {
    union { float f; unsigned int u; } v; v.f = f;
    unsigned int r = v.u + 0x7FFFu + ((v.u >> 16) & 1u);
    return (unsigned short)(r >> 16);
}

// Load up to 8 consecutive f32 (zero-masked at K=300 boundary), scale, convert
// to bf16, return packed uint4 (8 bf16, fragment j-order = ascending k).
__device__ inline uint4 load8_cvt_s(const float* src, bool rowok, int krem, float scale) {
    f32x4 v0 = {0.f,0.f,0.f,0.f}, v1 = {0.f,0.f,0.f,0.f};
    if (rowok) {
        if (krem >= 8)      { v0 = *(const f32x4*)src; v1 = *(const f32x4*)(src + 4); }
        else if (krem >= 4) { v0 = *(const f32x4*)src; }
    }
    v0 *= scale; v1 *= scale;
    uint4 p;
    p.x = (unsigned)f2bf(v0[0]) | ((unsigned)f2bf(v0[1]) << 16);
    p.y = (unsigned)f2bf(v0[2]) | ((unsigned)f2bf(v0[3]) << 16);
    p.z = (unsigned)f2bf(v1[0]) | ((unsigned)f2bf(v1[1]) << 16);
    p.w = (unsigned)f2bf(v1[2]) | ((unsigned)f2bf(v1[3]) << 16);
    return p;
}

__device__ inline uint4 load8_cvt(const float* src, bool rowok, int krem) {
    return load8_cvt_s(src, rowok, krem, 1.0f);
}

// ---------------------------------------------------------------------------
// K1: A[m][n] = -log2e * (sum_k X[m][k]*W1[n][k] + b1[n])   (bf16 MFMA)
// ---------------------------------------------------------------------------
__global__ __launch_bounds__(256) void gemm_in(
    const float* __restrict__ X, const float* __restrict__ W1,
    const float* __restrict__ b1, float* __restrict__ A)
{
    __shared__ unsigned short alds[8 * 64 * 8];
    __shared__ unsigned short blds[10 * 64 * 8];
    const int tid = threadIdx.x;
    const int w = tid >> 6, l = tid & 63, lg = l >> 4, ln = l & 15;
    const size_t m0 = (size_t)blockIdx.x * 128;
    const int n0 = blockIdx.y * 160;

    f32x4 acc[2][10];
    #pragma unroll
    for (int q = 0; q < 2; ++q)
        #pragma unroll
        for (int nt = 0; nt < 10; ++nt) acc[q][nt] = (f32x4){0.f,0.f,0.f,0.f};

    for (int kt = 0; kt < 10; ++kt) {
        const int kc = kt * 32;
        __syncthreads();
        #pragma unroll
        for (int rep = 0; rep < 2; ++rep) {
            int e = tid + rep * 256;
            int row = e >> 2, kh = e & 3;
            int k0 = kc + kh * 8;
            uint4 p = load8_cvt(X + (m0 + row) * 300 + k0, true, 300 - k0);
            *(uint4*)&alds[(((row >> 4) * 64) + kh * 16 + (row & 15)) * 8] = p;
        }
        #pragma unroll
        for (int rep = 0; rep < 3; ++rep) {
            int e = tid + rep * 256;
            if (e < 640) {
                int nn = e >> 2, kh = e & 3;
                int n = n0 + nn;
                int k0 = kc + kh * 8;
                uint4 p = load8_cvt(W1 + (size_t)n * 600 + k0, n < 300, 300 - k0);
                *(uint4*)&blds[(((nn >> 4) * 64) + kh * 16 + (nn & 15)) * 8] = p;
            }
        }
        __syncthreads();
        bf16x8 bfr[10];
        #pragma unroll
        for (int nt = 0; nt < 10; ++nt) bfr[nt] = *(const bf16x8*)&blds[(nt * 64 + l) * 8];
        #pragma unroll
        for (int q = 0; q < 2; ++q) {
            bf16x8 afr = *(const bf16x8*)&alds[((w * 2 + q) * 64 + l) * 8];
            #pragma unroll
            for (int nt = 0; nt < 10; ++nt)
                acc[q][nt] = __builtin_amdgcn_mfma_f32_16x16x32_bf16(afr, bfr[nt], acc[q][nt], 0, 0, 0);
        }
    }

    #pragma unroll
    for (int q = 0; q < 2; ++q)
        #pragma unroll
        for (int nt = 0; nt < 10; ++nt) {
            int n = n0 + nt * 16 + ln;
            if (n < 300) {
                float bias = b1[n];
                size_t mr = m0 + (w * 2 + q) * 16 + lg * 4;
                #pragma unroll
                for (int i = 0; i < 4; ++i)
                    A[(mr + i) * 300 + n] = (acc[q][nt][i] + bias) * NL2E;
            }
        }
}

#define QOK(q) ((q) < 2 || w4)

// ---------------------------------------------------------------------------
// K2-WS: recurrence, h stored TIME-MAJOR to d_ws: h_T4[t][rg=r/4][b][4 bf16].
// Stores are coalesced (16 lanes -> 128B runs, ~8 lines/instr vs 64 before).
// A region in d_out is never written -> no delayed-store race apparatus.
// 8 blocks x 512 thr; W1h A-frags in regs; h via dbuf LDS B-frags; exp2
// sigmoid; one lgkmcnt(0)+s_barrier per step; globals stay in flight.
// ---------------------------------------------------------------------------
#define K2W_STEP(P, tval, ASLOT, APTR)                                          \
    {                                                                           \
        const int t = (tval);                                                   \
        bf16x8 bfr[10];                                                         \
        _Pragma("unroll")                                                       \
        for (int kt = 0; kt < 10; ++kt)                                         \
            bfr[kt] = *(const bf16x8*)&hlds[P][(kt * 64 + l) * 8];              \
        f32x4 acc[3], accB[3];                                                  \
        _Pragma("unroll")                                                       \
        for (int q = 0; q < 3; ++q) {                                           \
            acc[q] = QOK(q) ? ASLOT[q] : (f32x4){0.f,0.f,0.f,0.f};              \
            accB[q] = (f32x4){0.f,0.f,0.f,0.f};                                 \
        }                                                                       \
        _Pragma("unroll")                                                       \
        for (int q = 0; q < 3; ++q)                                             \
            if (QOK(q)) ASLOT[q] = *(const f32x4*)(APTR + rq[q] * 4);           \
        APTR += 2400;                                                           \
        __builtin_amdgcn_s_setprio(1);                                          \
        _Pragma("unroll")                                                       \
        for (int kt = 0; kt < 5; ++kt) {                                        \
            acc[0]  = __builtin_amdgcn_mfma_f32_16x16x32_bf16(afrag[0][kt],   bfr[kt],   acc[0],  0, 0, 0); \
            accB[0] = __builtin_amdgcn_mfma_f32_16x16x32_bf16(afrag[0][kt+5], bfr[kt+5], accB[0], 0, 0, 0); \
            acc[1]  = __builtin_amdgcn_mfma_f32_16x16x32_bf16(afrag[1][kt],   bfr[kt],   acc[1],  0, 0, 0); \
            accB[1] = __builtin_amdgcn_mfma_f32_16x16x32_bf16(afrag[1][kt+5], bfr[kt+5], accB[1], 0, 0, 0); \
            if (w4) {                                                           \
                acc[2]  = __builtin_amdgcn_mfma_f32_16x16x32_bf16(afrag[2][kt],   bfr[kt],   acc[2],  0, 0, 0); \
                accB[2] = __builtin_amdgcn_mfma_f32_16x16x32_bf16(afrag[2][kt+5], bfr[kt+5], accB[2], 0, 0, 0); \
            }                                                                   \
        }                                                                       \
        __builtin_amdgcn_s_setprio(0);                                          \
        _Pragma("unroll")                                                       \
        for (int q = 0; q < 3; ++q) {                                           \
            if (!QOK(q)) continue;                                              \
            f32x4 hv;                                                           \
            _Pragma("unroll")                                                   \
            for (int i = 0; i < 4; ++i) {                                       \
                float zn = acc[q][i] + accB[q][i];      /* = -z*log2e */        \
                float ex, sg;                                                   \
                asm("v_exp_f32 %0, %1" : "=v"(ex) : "v"(zn));                   \
                asm("v_rcp_f32 %0, %1" : "=v"(sg) : "v"(1.0f + ex));            \
                hv[i] = sg;                                                     \
            }                                                                   \
            unsigned plo, phi;                                                  \
            asm("v_cvt_pk_bf16_f32 %0, %1, %2" : "=v"(plo) : "v"(hv[0]), "v"(hv[1])); \
            asm("v_cvt_pk_bf16_f32 %0, %1, %2" : "=v"(phi) : "v"(hv[2]), "v"(hv[3])); \
            uint2 pk; pk.x = plo; pk.y = phi;                                   \
            *(uint2*)((char*)hlds + ((P) ^ 1) * 10240 + ldsoff[q]) = pk;        \
            if (rq[q] < 300) {                                                  \
                *(uint2*)(q == 0 ? HW0 : (q == 1 ? HW1 : HW2)) = pk;            \
                if (t == T_ - 1)                                                \
                    *(f32x4*)(hfinal + bb * 300 + rq[q]) = hv;                  \
            }                                                                   \
        }                                                                       \
        HW0 += 76800; HW1 += 76800; HW2 += 76800;                               \
        asm volatile("s_waitcnt lgkmcnt(0)" ::: "memory");                      \
        __builtin_amdgcn_s_barrier();                                           \
        asm volatile("" ::: "memory");                                          \
    }

__global__ __launch_bounds__(512) void elman_rec_ws(
    const float* __restrict__ W1, float* __restrict__ buf,
    float* __restrict__ hfinal, char* __restrict__ hws)
{
    __shared__ unsigned short hlds[2][10 * 64 * 8];   // 2 x 10240 B
    const int tid = threadIdx.x;
    const int w = tid >> 6, l = tid & 63, lg = l >> 4, ln = l & 15;
    const bool w4 = (w < 4);
    const int bb = blockIdx.x * 16 + ln;    // this lane's batch (B/C column)

    int rq[3], ldsoff[3];
    #pragma unroll
    for (int q = 0; q < 3; ++q) {
        int tile = w4 ? (3 * w + q) : (12 + 2 * (w - 4) + q);
        int r = tile * 16 + 4 * lg;
        rq[q] = r;
        ldsoff[q] = (((r >> 5) * 64 + ((r >> 3) & 3) * 16 + ln) * 8 + (r & 7)) * 2;
    }

    // W1h A-fragments, scaled by -log2e (rows >=300, k>=300 zeroed)
    bf16x8 afrag[3][10];
    #pragma unroll
    for (int q = 0; q < 3; ++q) {
        #pragma unroll
        for (int kt = 0; kt < 10; ++kt) {
            bool qa = (q < 2) || w4;
            int tile = w4 ? (3 * w + q) : (12 + 2 * (w - 4) + q);
            int r = tile * 16 + ln;
            int k0 = kt * 32 + lg * 8;
            uint4 p = load8_cvt_s(W1 + (size_t)r * 600 + 300 + k0,
                                  qa && r < 300, 300 - k0, NL2E);
            union { uint4 u; bf16x8 s; } cv; cv.u = p;
            afrag[q][kt] = cv.s;
        }
    }

    for (int i = tid; i < 10 * 64 * 8; i += 512) hlds[0][i] = 0;

    // per-lane pointers: A' reads (batch-major, d_out), h_T4 writes (ws)
    const char* abase = (const char*)(buf + (size_t)bb * T_ * 300);
    char* HW0 = hws + (size_t)(rq[0] >> 2) * 1024 + bb * 8;
    char* HW1 = hws + (size_t)(rq[1] >> 2) * 1024 + bb * 8;
    char* HW2 = hws + (size_t)(rq[2] >> 2) * 1024 + bb * 8;

    f32x4 A0[3], A1[3];
    #pragma unroll
    for (int q = 0; q < 3; ++q)
        if (QOK(q)) {
            A0[q] = *(const f32x4*)(abase + rq[q] * 4);
            A1[q] = *(const f32x4*)(abase + 1200 + rq[q] * 4);
        }
    const char* aptr0 = abase + 2400;   // even steps load t+2
    const char* aptr1 = abase + 3600;   // odd steps load t+2
    __syncthreads();

    for (int t2 = 0; t2 < T_; t2 += 2) {
        K2W_STEP(0, t2,     A0, aptr0)
        K2W_STEP(1, t2 + 1, A1, aptr1)
    }
}

// ---------------------------------------------------------------------------
// K3-T: out[b][t][n] = sum_r h_T4[t][r][b]*W2[n][r] + b2[n].
// One block per t (grid 1024, 256 thr): M=128 batches (8 m-tiles, 2/wave),
// N=300 (19 n-tiles), K=300. h staged coalesced from ws ([rg][b][4] -> LDS
// [8][132][4] padded, 2-way-free reads). Writes overwrite consumed A' region
// in d_out — K2 finished entirely, so any order is safe.
// ---------------------------------------------------------------------------
__global__ __launch_bounds__(256) void gemm_out_t(
    const char* __restrict__ hws, const float* __restrict__ W2,
    const float* __restrict__ b2, float* __restrict__ out)
{
    __shared__ unsigned short ahs[8 * 132 * 4];    // 8448 B
    __shared__ unsigned short blds[19 * 64 * 8];   // 19456 B
    const int tid = threadIdx.x;
    const int w = tid >> 6, l = tid & 63, lg = l >> 4, ln = l & 15;
    const int t = blockIdx.x;
    const char* hbase = hws + (size_t)t * 76800;

    f32x4 acc[2][19];
    #pragma unroll
    for (int q = 0; q < 2; ++q)
        #pragma unroll
        for (int nt = 0; nt < 19; ++nt) acc[q][nt] = (f32x4){0.f,0.f,0.f,0.f};

    for (int kt = 0; kt < 10; ++kt) {
        const int kc = kt * 32;
        __syncthreads();
        // stage h: rg-chunk kt*8..kt*8+7 x 128 b (zero beyond rg 74)
        #pragma unroll
        for (int it = 0; it < 4; ++it) {
            int e = tid + it * 256;            // < 1024
            int rg = e >> 7, b = e & 127;
            int rgg = kt * 8 + rg;
            uint2 v = make_uint2(0u, 0u);
            if (rgg < 75) v = *(const uint2*)(hbase + (size_t)rgg * 1024 + b * 8);
            *(uint2*)&ahs[(rg * 132 + b) * 4] = v;
        }
        // stage W2 tile: 304 n-rows x 32 k
        #pragma unroll
        for (int rep = 0; rep < 5; ++rep) {
            int e = tid + rep * 256;
            if (e < 1216) {
                int nn = e >> 2, kh = e & 3;
                int k0 = kc + kh * 8;
                uint4 p = load8_cvt(W2 + (size_t)nn * 300 + k0, nn < 300, 300 - k0);
                *(uint4*)&blds[(((nn >> 4) * 64) + kh * 16 + (nn & 15)) * 8] = p;
            }
        }
        __syncthreads();
        bf16x8 bfr[19];
        #pragma unroll
        for (int nt = 0; nt < 19; ++nt) bfr[nt] = *(const bf16x8*)&blds[(nt * 64 + l) * 8];
        #pragma unroll
        for (int q = 0; q < 2; ++q) {
            int b = (w * 2 + q) * 16 + ln;
            uint2 u0 = *(const uint2*)&ahs[((2 * lg)     * 132 + b) * 4];
            uint2 u1 = *(const uint2*)&ahs[((2 * lg + 1) * 132 + b) * 4];
            union { uint4 u; bf16x8 s; } cv;
            cv.u.x = u0.x; cv.u.y = u0.y; cv.u.z = u1.x; cv.u.w = u1.y;
            bf16x8 afr = cv.s;
            #pragma unroll
            for (int nt = 0; nt < 19; ++nt)
                acc[q][nt] = __builtin_amdgcn_mfma_f32_16x16x32_bf16(afr, bfr[nt], acc[q][nt], 0, 0, 0);
        }
    }

    #pragma unroll
    for (int q = 0; q < 2; ++q)
        #pragma unroll
        for (int nt = 0; nt < 19; ++nt) {
            int n = nt * 16 + ln;
            if (n < 300) {
                float bias = b2[n];
                int b0r = (w * 2 + q) * 16 + lg * 4;
                #pragma unroll
                for (int i = 0; i < 4; ++i)
                    out[((size_t)(b0r + i) * T_ + t) * 300 + n] = acc[q][nt][i] + bias;
            }
        }
}

// ---------------------------------------------------------------------------
// FALLBACK K2 (R9): packed h into d_out, delayed stores (race-free scheme).
// ---------------------------------------------------------------------------
#define K2_STEP(P, tval, ASLOT, APTR, HPME, HPOTHER)                            \
    {                                                                           \
        const int t = (tval);                                                   \
        const int tt = t - 1;                                                   \
        const size_t so = (size_t)(tt >> 6) * 76800 + (size_t)(tt & 63) * 600;  \
        bf16x8 bfr[10];                                                         \
        _Pragma("unroll")                                                       \
        for (int kt = 0; kt < 10; ++kt)                                         \
            bfr[kt] = *(const bf16x8*)&hlds[P][(kt * 64 + l) * 8];              \
        f32x4 acc[3], accB[3];                                                  \
        _Pragma("unroll")                                                       \
        for (int q = 0; q < 3; ++q) {                                           \
            acc[q] = QOK(q) ? ASLOT[q] : (f32x4){0.f,0.f,0.f,0.f};              \
            accB[q] = (f32x4){0.f,0.f,0.f,0.f};                                 \
        }                                                                       \
        _Pragma("unroll")                                                       \
        for (int q = 0; q < 3; ++q)                                             \
            if (QOK(q)) ASLOT[q] = *(const f32x4*)(APTR + rq[q] * 4);           \
        APTR += 2400;                                                           \
        __builtin_amdgcn_s_setprio(1);                                          \
        _Pragma("unroll")                                                       \
        for (int kt = 0; kt < 5; ++kt) {                                        \
            acc[0]  = __builtin_amdgcn_mfma_f32_16x16x32_bf16(afrag[0][kt],   bfr[kt],   acc[0],  0, 0, 0); \
            accB[0] = __builtin_amdgcn_mfma_f32_16x16x32_bf16(afrag[0][kt+5], bfr[kt+5], accB[0], 0, 0, 0); \
            acc[1]  = __builtin_amdgcn_mfma_f32_16x16x32_bf16(afrag[1][kt],   bfr[kt],   acc[1],  0, 0, 0); \
            accB[1] = __builtin_amdgcn_mfma_f32_16x16x32_bf16(afrag[1][kt+5], bfr[kt+5], accB[1], 0, 0, 0); \
            if (w4) {                                                           \
                acc[2]  = __builtin_amdgcn_mfma_f32_16x16x32_bf16(afrag[2][kt],   bfr[kt],   acc[2],  0, 0, 0); \
                accB[2] = __builtin_amdgcn_mfma_f32_16x16x32_bf16(afrag[2][kt+5], bfr[kt+5], accB[2], 0, 0, 0); \
            }                                                                   \
        }                                                                       \
        __builtin_amdgcn_s_setprio(0);                                          \
        _Pragma("unroll")                                                       \
        for (int q = 0; q < 3; ++q) {                                           \
            if (!QOK(q)) continue;                                              \
            f32x4 hv;                                                           \
            _Pragma("unroll")                                                   \
            for (int i = 0; i < 4; ++i) {                                       \
                float zn = acc[q][i] + accB[q][i];                              \
                float ex, sg;                                                   \
                asm("v_exp_f32 %0, %1" : "=v"(ex) : "v"(zn));                   \
                asm("v_rcp_f32 %0, %1" : "=v"(sg) : "v"(1.0f + ex));            \
                hv[i] = sg;                                                     \
            }                                                                   \
            unsigned plo, phi;                                                  \
            asm("v_cvt_pk_bf16_f32 %0, %1, %2" : "=v"(plo) : "v"(hv[0]), "v"(hv[1])); \
            asm("v_cvt_pk_bf16_f32 %0, %1, %2" : "=v"(phi) : "v"(hv[2]), "v"(hv[3])); \
            HPME[q].x = plo; HPME[q].y = phi;                                   \
            *(uint2*)((char*)hlds + ((P) ^ 1) * 10240 + ldsoff[q]) = HPME[q];   \
            if (t > 0 && rq[q] < 300)                                           \
                *(uint2*)(sbase + so + rq[q] * 2) = HPOTHER[q];                 \
        }                                                                       \
        asm volatile("s_waitcnt lgkmcnt(0)" ::: "memory");                      \
        __builtin_amdgcn_s_barrier();                                           \
        asm volatile("" ::: "memory");                                          \
    }

__global__ __launch_bounds__(512) void elman_rec_mfma(
    const float* __restrict__ W1, float* __restrict__ buf,
    float* __restrict__ hfinal)
{
    __shared__ unsigned short hlds[2][10 * 64 * 8];
    const int tid = threadIdx.x;
    const int w = tid >> 6, l = tid & 63, lg = l >> 4, ln = l & 15;
    const bool w4 = (w < 4);
    const int bb = blockIdx.x * 16 + ln;

    int rq[3], ldsoff[3];
    #pragma unroll
    for (int q = 0; q < 3; ++q) {
        int tile = w4 ? (3 * w + q) : (12 + 2 * (w - 4) + q);
        int r = tile * 16 + 4 * lg;
        rq[q] = r;
        ldsoff[q] = (((r >> 5) * 64 + ((r >> 3) & 3) * 16 + ln) * 8 + (r & 7)) * 2;
    }

    bf16x8 afrag[3][10];
    #pragma unroll
    for (int q = 0; q < 3; ++q) {
        #pragma unroll
        for (int kt = 0; kt < 10; ++kt) {
            bool qa = (q < 2) || w4;
            int tile = w4 ? (3 * w + q) : (12 + 2 * (w - 4) + q);
            int r = tile * 16 + ln;
            int k0 = kt * 32 + lg * 8;
            uint4 p = load8_cvt_s(W1 + (size_t)r * 600 + 300 + k0,
                                  qa && r < 300, 300 - k0, NL2E);
            union { uint4 u; bf16x8 s; } cv; cv.u = p;
            afrag[q][kt] = cv.s;
        }
    }

    for (int i = tid; i < 10 * 64 * 8; i += 512) hlds[0][i] = 0;

    const char* abase = (const char*)(buf + (size_t)bb * T_ * 300);
    char* sbase = (char*)buf + (size_t)bb * 16 * 76800;

    f32x4 A0[3], A1[3];
    #pragma unroll
    for (int q = 0; q < 3; ++q)
        if (QOK(q)) {
            A0[q] = *(const f32x4*)(abase + rq[q] * 4);
            A1[q] = *(const f32x4*)(abase + 1200 + rq[q] * 4);
        }
    const char* aptr0 = abase + 2400;
    const char* aptr1 = abase + 3600;
    uint2 hpA[3], hpB[3];
    __syncthreads();

    for (int t2 = 0; t2 < T_; t2 += 2) {
        K2_STEP(0, t2,     A0, aptr0, hpA, hpB)
        K2_STEP(1, t2 + 1, A1, aptr1, hpB, hpA)
    }

    {
        const int tt = T_ - 1;
        const size_t so = (size_t)(tt >> 6) * 76800 + (size_t)(tt & 63) * 600;
        #pragma unroll
        for (int q = 0; q < 3; ++q)
            if (QOK(q) && rq[q] < 300) {
                *(uint2*)(sbase + so + rq[q] * 2) = hpB[q];
                f32x4 hv;
                union { float f; unsigned u; } c0, c1, c2, c3;
                c0.u = hpB[q].x << 16; c1.u = hpB[q].x & 0xFFFF0000u;
                c2.u = hpB[q].y << 16; c3.u = hpB[q].y & 0xFFFF0000u;
                hv[0] = c0.f; hv[1] = c1.f; hv[2] = c2.f; hv[3] = c3.f;
                *(f32x4*)(hfinal + bb * 300 + rq[q]) = hv;
            }
    }
}

// ---------------------------------------------------------------------------
// FALLBACK K3: in place over packed-h d_out (one block per 64-row chunk).
// ---------------------------------------------------------------------------
__global__ __launch_bounds__(256) void gemm_out(
    float* __restrict__ buf, const float* __restrict__ W2,
    const float* __restrict__ b2)
{
    __shared__ unsigned short alds[4 * 64 * 8];
    __shared__ unsigned short blds[19 * 64 * 8];
    const int tid = threadIdx.x;
    const int w = tid >> 6, l = tid & 63, lg = l >> 4, ln = l & 15;
    const size_t chunk = blockIdx.x;
    const char* pbase = (const char*)buf + chunk * 76800;

    f32x4 acc[19];
    #pragma unroll
    for (int nt = 0; nt < 19; ++nt) acc[nt] = (f32x4){0.f,0.f,0.f,0.f};

    for (int kt = 0; kt < 10; ++kt) {
        const int kc = kt * 32;
        __syncthreads();
        {
            int row = tid >> 2, kh = tid & 3;
            int k0 = kc + kh * 8;
            const char* p = pbase + row * 600;
            uint2 lo = make_uint2(0u, 0u), hi = make_uint2(0u, 0u);
            int krem = 300 - k0;
            if (krem >= 8)      { lo = *(const uint2*)(p + k0 * 2); hi = *(const uint2*)(p + k0 * 2 + 8); }
            else if (krem >= 4) { lo = *(const uint2*)(p + k0 * 2); }
            uint4 pk; pk.x = lo.x; pk.y = lo.y; pk.z = hi.x; pk.w = hi.y;
            *(uint4*)&alds[(((row >> 4) * 64) + kh * 16 + (row & 15)) * 8] = pk;
        }
        #pragma unroll
        for (int rep = 0; rep < 5; ++rep) {
            int e = tid + rep * 256;
            if (e < 1216) {
                int nn = e >> 2, kh = e & 3;
                int k0 = kc + kh * 8;
                uint4 p = load8_cvt(W2 + (size_t)nn * 300 + k0, nn < 300, 300 - k0);
                *(uint4*)&blds[(((nn >> 4) * 64) + kh * 16 + (nn & 15)) * 8] = p;
            }
        }
        __syncthreads();
        bf16x8 afr = *(const bf16x8*)&alds[(w * 64 + l) * 8];
        #pragma unroll
        for (int nt = 0; nt < 19; ++nt) {
            bf16x8 bfr = *(const bf16x8*)&blds[(nt * 64 + l) * 8];
            acc[nt] = __builtin_amdgcn_mfma_f32_16x16x32_bf16(afr, bfr, acc[nt], 0, 0, 0);
        }
    }

    float* frow = buf + chunk * 19200;
    #pragma unroll
    for (int nt = 0; nt < 19; ++nt) {
        int n = nt * 16 + ln;
        if (n < 300) {
            float bias = b2[n];
            int mr = w * 16 + lg * 4;
            #pragma unroll
            for (int i = 0; i < 4; ++i)
                frow[(mr + i) * 300 + n] = acc[nt][i] + bias;
        }
    }
}

// ---------------------------------------------------------------------------
extern "C" void kernel_launch(void* const* d_in, const int* in_sizes, int n_in,
                              void* d_out, int out_size, void* d_ws, size_t ws_size,
                              hipStream_t stream)
{
    const float* x  = (const float*)d_in[0];
    const float* W1 = (const float*)d_in[1];
    const float* b1 = (const float*)d_in[2];
    const float* W2 = (const float*)d_in[3];
    const float* b2 = (const float*)d_in[4];

    float* out    = (float*)d_out;
    float* hfinal = out + (size_t)HB;

    gemm_in<<<dim3(1024, 2), 256, 0, stream>>>(x, W1, b1, out);

    const size_t HT4 = (size_t)T_ * 75 * 128 * 8;   // 78,643,200 B
    if (ws_size >= HT4) {
        elman_rec_ws<<<8, 512, 0, stream>>>(W1, out, hfinal, (char*)d_ws);
        gemm_out_t<<<1024, 256, 0, stream>>>((const char*)d_ws, W2, b2, out);
    } else {
        elman_rec_mfma<<<8, 512, 0, stream>>>(W1, out, hfinal);
        gemm_out<<<2048, 256, 0, stream>>>(out, W2, b2);
    }
}

// Round 11
// 1214.234 us; speedup vs baseline: 1.7598x; 1.1011x over previous
//
#include <hip/hip_runtime.h>

typedef __attribute__((ext_vector_type(4))) float f32x4;
typedef __attribute__((ext_vector_type(8))) short bf16x8;

#define B_   128
#define T_   1024
#define NROW 131072      // B*T
#define HB   (NROW*300)  // floats in the [B*T][300] matrix
#define NL2E -1.44269504088896340736f   // -log2(e)

__device__ inline unsigned short f2bf(float f) {
    union { float f; unsigned int u; } v; v.f = f;
    unsigned int r = v.u + 0x7FFFu + ((v.u >> 16) & 1u);
    return (unsigned short)(r >> 16);
}

// Load up to 8 consecutive f32 (zero-masked at K=300 boundary), scale, convert
// to bf16, return packed uint4 (8 bf16, fragment j-order = ascending k).
__device__ inline uint4 load8_cvt_s(const float* src, bool rowok, int krem, float scale) {
    f32x4 v0 = {0.f,0.f,0.f,0.f}, v1 = {0.f,0.f,0.f,0.f};
    if (rowok) {
        if (krem >= 8)      { v0 = *(const f32x4*)src; v1 = *(const f32x4*)(src + 4); }
        else if (krem >= 4) { v0 = *(const f32x4*)src; }
    }
    v0 *= scale; v1 *= scale;
    uint4 p;
    p.x = (unsigned)f2bf(v0[0]) | ((unsigned)f2bf(v0[1]) << 16);
    p.y = (unsigned)f2bf(v0[2]) | ((unsigned)f2bf(v0[3]) << 16);
    p.z = (unsigned)f2bf(v1[0]) | ((unsigned)f2bf(v1[1]) << 16);
    p.w = (unsigned)f2bf(v1[2]) | ((unsigned)f2bf(v1[3]) << 16);
    return p;
}

__device__ inline uint4 load8_cvt(const float* src, bool rowok, int krem) {
    return load8_cvt_s(src, rowok, krem, 1.0f);
}

// ---------------------------------------------------------------------------
// K1-T (ws path): A'_T4[t][rg=n/4][b][4 bf16] = -log2e*(x[b,t]·W1x^T + b1),
// packed bf16, time-major into d_ws. One block per t; M = n (19 tiles, W1x
// frags, NL2E-prescaled), N = b (8 tiles, x frags). Epilogue lane holds 4
// consecutive n for one b -> cvt_pk x2 -> uint2; 16 lanes = 128B runs.
// ---------------------------------------------------------------------------
__global__ __launch_bounds__(256) void gemm_in_t(
    const float* __restrict__ X, const float* __restrict__ W1,
    const float* __restrict__ b1, char* __restrict__ aws)
{
    __shared__ unsigned short wlds[19 * 64 * 8];   // W1x frag-linear (M=n)
    __shared__ unsigned short xlds[8 * 64 * 8];    // x frag-linear (N=b)
    const int tid = threadIdx.x;
    const int w = tid >> 6, l = tid & 63, lg = l >> 4, ln = l & 15;
    const int t = blockIdx.x;

    f32x4 acc[2][19];
    #pragma unroll
    for (int q = 0; q < 2; ++q)
        #pragma unroll
        for (int mt = 0; mt < 19; ++mt) acc[q][mt] = (f32x4){0.f,0.f,0.f,0.f};

    for (int kt = 0; kt < 10; ++kt) {
        const int kc = kt * 32;
        __syncthreads();
        // stage W1x tile: 304 n-rows x 32 k, NL2E-prescaled
        #pragma unroll
        for (int rep = 0; rep < 5; ++rep) {
            int e = tid + rep * 256;
            if (e < 1216) {
                int nn = e >> 2, kh = e & 3;
                int k0 = kc + kh * 8;
                uint4 p = load8_cvt_s(W1 + (size_t)nn * 600 + k0, nn < 300, 300 - k0, NL2E);
                *(uint4*)&wlds[(((nn >> 4) * 64) + kh * 16 + (nn & 15)) * 8] = p;
            }
        }
        // stage x tile: 128 b-rows x 32 k (row b at fixed t)
        #pragma unroll
        for (int rep = 0; rep < 2; ++rep) {
            int e = tid + rep * 256;           // < 512
            int row = e >> 2, kh = e & 3;
            int k0 = kc + kh * 8;
            uint4 p = load8_cvt(X + ((size_t)row * 1024 + t) * 300 + k0, true, 300 - k0);
            *(uint4*)&xlds[(((row >> 4) * 64) + kh * 16 + (row & 15)) * 8] = p;
        }
        __syncthreads();
        bf16x8 wfr[19];
        #pragma unroll
        for (int mt = 0; mt < 19; ++mt) wfr[mt] = *(const bf16x8*)&wlds[(mt * 64 + l) * 8];
        #pragma unroll
        for (int q = 0; q < 2; ++q) {
            bf16x8 xfr = *(const bf16x8*)&xlds[((w * 2 + q) * 64 + l) * 8];
            #pragma unroll
            for (int mt = 0; mt < 19; ++mt)
                acc[q][mt] = __builtin_amdgcn_mfma_f32_16x16x32_bf16(wfr[mt], xfr, acc[q][mt], 0, 0, 0);
        }
    }

    // epilogue: pack 4 consecutive n per lane, store coalesced to A'_T4
    char* tb = aws + (size_t)t * 76800;
    #pragma unroll
    for (int q = 0; q < 2; ++q) {
        int b = (w * 2 + q) * 16 + ln;
        #pragma unroll
        for (int mt = 0; mt < 19; ++mt) {
            int rg = mt * 4 + lg;
            if (rg < 75) {
                f32x4 bias = *(const f32x4*)(b1 + mt * 16 + lg * 4);
                float v0 = acc[q][mt][0] + bias[0] * NL2E;
                float v1 = acc[q][mt][1] + bias[1] * NL2E;
                float v2 = acc[q][mt][2] + bias[2] * NL2E;
                float v3 = acc[q][mt][3] + bias[3] * NL2E;
                unsigned plo, phi;
                asm("v_cvt_pk_bf16_f32 %0, %1, %2" : "=v"(plo) : "v"(v0), "v"(v1));
                asm("v_cvt_pk_bf16_f32 %0, %1, %2" : "=v"(phi) : "v"(v2), "v"(v3));
                uint2 pk; pk.x = plo; pk.y = phi;
                *(uint2*)(tb + (size_t)rg * 1024 + b * 8) = pk;
            }
        }
    }
}

#define QOK(q) ((q) < 2 || w4)

// ---------------------------------------------------------------------------
// K2-WS2: recurrence; A' read AND h written coalesced, in place in d_ws
// (h(t) overwrites A'(t): same lane, same address, load consumed before store
// issues -> race-free). 8 blocks x 512 thr; W1h bf16 A-frags in regs; h via
// dbuf LDS B-frags; exp2 sigmoid; one lgkmcnt(0)+s_barrier per step; globals
// stay in flight. SP[q] per parity advances 2*76800/step-pair; load at
// SP+153600 (t+2) -- unguarded, needs ws_size >= HT4 + 153600.
// ---------------------------------------------------------------------------
#define K2W_STEP(P, tval, AS, SP)                                               \
    {                                                                           \
        const int t = (tval);                                                   \
        bf16x8 bfr[10];                                                         \
        _Pragma("unroll")                                                       \
        for (int kt = 0; kt < 10; ++kt)                                         \
            bfr[kt] = *(const bf16x8*)&hlds[P][(kt * 64 + l) * 8];              \
        f32x4 acc[3], accB[3];                                                  \
        _Pragma("unroll")                                                       \
        for (int q = 0; q < 3; ++q) {                                           \
            union { float f; unsigned u; } u0, u1, u2, u3;                      \
            u0.u = AS[q].x << 16; u1.u = AS[q].x & 0xFFFF0000u;                 \
            u2.u = AS[q].y << 16; u3.u = AS[q].y & 0xFFFF0000u;                 \
            acc[q] = (f32x4){u0.f, u1.f, u2.f, u3.f};                           \
            accB[q] = (f32x4){0.f,0.f,0.f,0.f};                                 \
        }                                                                       \
        /* prefetch A'(t+2), coalesced */                                       \
        _Pragma("unroll")                                                       \
        for (int q = 0; q < 3; ++q)                                             \
            if (QOK(q)) AS[q] = *(const uint2*)(SP[q] + 153600);                \
        __builtin_amdgcn_s_setprio(1);                                          \
        _Pragma("unroll")                                                       \
        for (int kt = 0; kt < 5; ++kt) {                                        \
            acc[0]  = __builtin_amdgcn_mfma_f32_16x16x32_bf16(afrag[0][kt],   bfr[kt],   acc[0],  0, 0, 0); \
            accB[0] = __builtin_amdgcn_mfma_f32_16x16x32_bf16(afrag[0][kt+5], bfr[kt+5], accB[0], 0, 0, 0); \
            acc[1]  = __builtin_amdgcn_mfma_f32_16x16x32_bf16(afrag[1][kt],   bfr[kt],   acc[1],  0, 0, 0); \
            accB[1] = __builtin_amdgcn_mfma_f32_16x16x32_bf16(afrag[1][kt+5], bfr[kt+5], accB[1], 0, 0, 0); \
            if (w4) {                                                           \
                acc[2]  = __builtin_amdgcn_mfma_f32_16x16x32_bf16(afrag[2][kt],   bfr[kt],   acc[2],  0, 0, 0); \
                accB[2] = __builtin_amdgcn_mfma_f32_16x16x32_bf16(afrag[2][kt+5], bfr[kt+5], accB[2], 0, 0, 0); \
            }                                                                   \
        }                                                                       \
        __builtin_amdgcn_s_setprio(0);                                          \
        _Pragma("unroll")                                                       \
        for (int q = 0; q < 3; ++q) {                                           \
            if (!QOK(q)) continue;                                              \
            f32x4 hv;                                                           \
            _Pragma("unroll")                                                   \
            for (int i = 0; i < 4; ++i) {                                       \
                float zn = acc[q][i] + accB[q][i];      /* = -z*log2e */        \
                float ex, sg;                                                   \
                asm("v_exp_f32 %0, %1" : "=v"(ex) : "v"(zn));                   \
                asm("v_rcp_f32 %0, %1" : "=v"(sg) : "v"(1.0f + ex));            \
                hv[i] = sg;                                                     \
            }                                                                   \
            unsigned plo, phi;                                                  \
            asm("v_cvt_pk_bf16_f32 %0, %1, %2" : "=v"(plo) : "v"(hv[0]), "v"(hv[1])); \
            asm("v_cvt_pk_bf16_f32 %0, %1, %2" : "=v"(phi) : "v"(hv[2]), "v"(hv[3])); \
            uint2 pk; pk.x = plo; pk.y = phi;                                   \
            *(uint2*)((char*)hlds + ((P) ^ 1) * 10240 + ldsoff[q]) = pk;        \
            if (rq[q] < 300) {                                                  \
                *(uint2*)SP[q] = pk;          /* h(t) overwrites A'(t) */       \
                if (t == T_ - 1)                                                \
                    *(f32x4*)(hfinal + bb * 300 + rq[q]) = hv;                  \
            }                                                                   \
            SP[q] += 153600;                                                    \
        }                                                                       \
        asm volatile("s_waitcnt lgkmcnt(0)" ::: "memory");                      \
        __builtin_amdgcn_s_barrier();                                           \
        asm volatile("" ::: "memory");                                          \
    }

__global__ __launch_bounds__(512) void elman_rec_ws(
    const float* __restrict__ W1, float* __restrict__ hfinal,
    char* __restrict__ hws)
{
    __shared__ unsigned short hlds[2][10 * 64 * 8];   // 2 x 10240 B
    const int tid = threadIdx.x;
    const int w = tid >> 6, l = tid & 63, lg = l >> 4, ln = l & 15;
    const bool w4 = (w < 4);
    const int bb = blockIdx.x * 16 + ln;    // this lane's batch (B/C column)

    int rq[3], ldsoff[3];
    #pragma unroll
    for (int q = 0; q < 3; ++q) {
        int tile = w4 ? (3 * w + q) : (12 + 2 * (w - 4) + q);
        int r = tile * 16 + 4 * lg;
        rq[q] = r;
        ldsoff[q] = (((r >> 5) * 64 + ((r >> 3) & 3) * 16 + ln) * 8 + (r & 7)) * 2;
    }

    // W1h A-fragments, scaled by -log2e (rows >=300, k>=300 zeroed)
    bf16x8 afrag[3][10];
    #pragma unroll
    for (int q = 0; q < 3; ++q) {
        #pragma unroll
        for (int kt = 0; kt < 10; ++kt) {
            bool qa = (q < 2) || w4;
            int tile = w4 ? (3 * w + q) : (12 + 2 * (w - 4) + q);
            int r = tile * 16 + ln;
            int k0 = kt * 32 + lg * 8;
            uint4 p = load8_cvt_s(W1 + (size_t)r * 600 + 300 + k0,
                                  qa && r < 300, 300 - k0, NL2E);
            union { uint4 u; bf16x8 s; } cv; cv.u = p;
            afrag[q][kt] = cv.s;
        }
    }

    for (int i = tid; i < 10 * 64 * 8; i += 512) hlds[0][i] = 0;

    // per-lane ws pointers (rg clamped for pad rows; those lanes never store)
    char* SP0[3]; char* SP1[3];
    uint2 AS0[3], AS1[3];
    #pragma unroll
    for (int q = 0; q < 3; ++q) {
        int rgc = rq[q] >> 2; if (rgc > 74) rgc = 74;
        char* base = hws + (size_t)rgc * 1024 + bb * 8;
        SP0[q] = base;            // even steps: t = 0, 2, ...
        SP1[q] = base + 76800;    // odd steps:  t = 1, 3, ...
        if (QOK(q)) {
            AS0[q] = *(const uint2*)SP0[q];   // A'(0)
            AS1[q] = *(const uint2*)SP1[q];   // A'(1)
        }
    }
    __syncthreads();

    for (int t2 = 0; t2 < T_; t2 += 2) {
        K2W_STEP(0, t2,     AS0, SP0)
        K2W_STEP(1, t2 + 1, AS1, SP1)
    }
}

// ---------------------------------------------------------------------------
// K3-T: out[b][t][n] = sum_r h_T4[t][r][b]*W2[n][r] + b2[n].
// One block per t (grid 1024, 256 thr). h staged coalesced from ws; writes
// go straight to d_out (nothing else writes it on the ws path).
// ---------------------------------------------------------------------------
__global__ __launch_bounds__(256) void gemm_out_t(
    const char* __restrict__ hws, const float* __restrict__ W2,
    const float* __restrict__ b2, float* __restrict__ out)
{
    __shared__ unsigned short ahs[8 * 132 * 4];    // 8448 B
    __shared__ unsigned short blds[19 * 64 * 8];   // 19456 B
    const int tid = threadIdx.x;
    const int w = tid >> 6, l = tid & 63, lg = l >> 4, ln = l & 15;
    const int t = blockIdx.x;
    const char* hbase = hws + (size_t)t * 76800;

    f32x4 acc[2][19];
    #pragma unroll
    for (int q = 0; q < 2; ++q)
        #pragma unroll
        for (int nt = 0; nt < 19; ++nt) acc[q][nt] = (f32x4){0.f,0.f,0.f,0.f};

    for (int kt = 0; kt < 10; ++kt) {
        const int kc = kt * 32;
        __syncthreads();
        // stage h: rg-chunk kt*8..kt*8+7 x 128 b (zero beyond rg 74)
        #pragma unroll
        for (int it = 0; it < 4; ++it) {
            int e = tid + it * 256;            // < 1024
            int rg = e >> 7, b = e & 127;
            int rgg = kt * 8 + rg;
            uint2 v = make_uint2(0u, 0u);
            if (rgg < 75) v = *(const uint2*)(hbase + (size_t)rgg * 1024 + b * 8);
            *(uint2*)&ahs[(rg * 132 + b) * 4] = v;
        }
        // stage W2 tile: 304 n-rows x 32 k
        #pragma unroll
        for (int rep = 0; rep < 5; ++rep) {
            int e = tid + rep * 256;
            if (e < 1216) {
                int nn = e >> 2, kh = e & 3;
                int k0 = kc + kh * 8;
                uint4 p = load8_cvt(W2 + (size_t)nn * 300 + k0, nn < 300, 300 - k0);
                *(uint4*)&blds[(((nn >> 4) * 64) + kh * 16 + (nn & 15)) * 8] = p;
            }
        }
        __syncthreads();
        bf16x8 bfr[19];
        #pragma unroll
        for (int nt = 0; nt < 19; ++nt) bfr[nt] = *(const bf16x8*)&blds[(nt * 64 + l) * 8];
        #pragma unroll
        for (int q = 0; q < 2; ++q) {
            int b = (w * 2 + q) * 16 + ln;
            uint2 u0 = *(const uint2*)&ahs[((2 * lg)     * 132 + b) * 4];
            uint2 u1 = *(const uint2*)&ahs[((2 * lg + 1) * 132 + b) * 4];
            union { uint4 u; bf16x8 s; } cv;
            cv.u.x = u0.x; cv.u.y = u0.y; cv.u.z = u1.x; cv.u.w = u1.y;
            bf16x8 afr = cv.s;
            #pragma unroll
            for (int nt = 0; nt < 19; ++nt)
                acc[q][nt] = __builtin_amdgcn_mfma_f32_16x16x32_bf16(afr, bfr[nt], acc[q][nt], 0, 0, 0);
        }
    }

    #pragma unroll
    for (int q = 0; q < 2; ++q)
        #pragma unroll
        for (int nt = 0; nt < 19; ++nt) {
            int n = nt * 16 + ln;
            if (n < 300) {
                float bias = b2[n];
                int b0r = (w * 2 + q) * 16 + lg * 4;
                #pragma unroll
                for (int i = 0; i < 4; ++i)
                    out[((size_t)(b0r + i) * T_ + t) * 300 + n] = acc[q][nt][i] + bias;
            }
        }
}

// ---------------------------------------------------------------------------
// FALLBACK K1: A' f32 into d_out (batch-major).
// ---------------------------------------------------------------------------
__global__ __launch_bounds__(256) void gemm_in(
    const float* __restrict__ X, const float* __restrict__ W1,
    const float* __restrict__ b1, float* __restrict__ A)
{
    __shared__ unsigned short alds[8 * 64 * 8];
    __shared__ unsigned short blds[10 * 64 * 8];
    const int tid = threadIdx.x;
    const int w = tid >> 6, l = tid & 63, lg = l >> 4, ln = l & 15;
    const size_t m0 = (size_t)blockIdx.x * 128;
    const int n0 = blockIdx.y * 160;

    f32x4 acc[2][10];
    #pragma unroll
    for (int q = 0; q < 2; ++q)
        #pragma unroll
        for (int nt = 0; nt < 10; ++nt) acc[q][nt] = (f32x4){0.f,0.f,0.f,0.f};

    for (int kt = 0; kt < 10; ++kt) {
        const int kc = kt * 32;
        __syncthreads();
        #pragma unroll
        for (int rep = 0; rep < 2; ++rep) {
            int e = tid + rep * 256;
            int row = e >> 2, kh = e & 3;
            int k0 = kc + kh * 8;
            uint4 p = load8_cvt(X + (m0 + row) * 300 + k0, true, 300 - k0);
            *(uint4*)&alds[(((row >> 4) * 64) + kh * 16 + (row & 15)) * 8] = p;
        }
        #pragma unroll
        for (int rep = 0; rep < 3; ++rep) {
            int e = tid + rep * 256;
            if (e < 640) {
                int nn = e >> 2, kh = e & 3;
                int n = n0 + nn;
                int k0 = kc + kh * 8;
                uint4 p = load8_cvt(W1 + (size_t)n * 600 + k0, n < 300, 300 - k0);
                *(uint4*)&blds[(((nn >> 4) * 64) + kh * 16 + (nn & 15)) * 8] = p;
            }
        }
        __syncthreads();
        bf16x8 bfr[10];
        #pragma unroll
        for (int nt = 0; nt < 10; ++nt) bfr[nt] = *(const bf16x8*)&blds[(nt * 64 + l) * 8];
        #pragma unroll
        for (int q = 0; q < 2; ++q) {
            bf16x8 afr = *(const bf16x8*)&alds[((w * 2 + q) * 64 + l) * 8];
            #pragma unroll
            for (int nt = 0; nt < 10; ++nt)
                acc[q][nt] = __builtin_amdgcn_mfma_f32_16x16x32_bf16(afr, bfr[nt], acc[q][nt], 0, 0, 0);
        }
    }

    #pragma unroll
    for (int q = 0; q < 2; ++q)
        #pragma unroll
        for (int nt = 0; nt < 10; ++nt) {
            int n = n0 + nt * 16 + ln;
            if (n < 300) {
                float bias = b1[n];
                size_t mr = m0 + (w * 2 + q) * 16 + lg * 4;
                #pragma unroll
                for (int i = 0; i < 4; ++i)
                    A[(mr + i) * 300 + n] = (acc[q][nt][i] + bias) * NL2E;
            }
        }
}

// ---------------------------------------------------------------------------
// FALLBACK K2 (R9): packed h into d_out, delayed stores (race-free scheme).
// ---------------------------------------------------------------------------
#define K2_STEP(P, tval, ASLOT, APTR, HPME, HPOTHER)                            \
    {                                                                           \
        const int t = (tval);                                                   \
        const int tt = t - 1;                                                   \
        const size_t so = (size_t)(tt >> 6) * 76800 + (size_t)(tt & 63) * 600;  \
        bf16x8 bfr[10];                                                         \
        _Pragma("unroll")                                                       \
        for (int kt = 0; kt < 10; ++kt)                                         \
            bfr[kt] = *(const bf16x8*)&hlds[P][(kt * 64 + l) * 8];              \
        f32x4 acc[3], accB[3];                                                  \
        _Pragma("unroll")                                                       \
        for (int q = 0; q < 3; ++q) {                                           \
            acc[q] = QOK(q) ? ASLOT[q] : (f32x4){0.f,0.f,0.f,0.f};              \
            accB[q] = (f32x4){0.f,0.f,0.f,0.f};                                 \
        }                                                                       \
        _Pragma("unroll")                                                       \
        for (int q = 0; q < 3; ++q)                                             \
            if (QOK(q)) ASLOT[q] = *(const f32x4*)(APTR + rq[q] * 4);           \
        APTR += 2400;                                                           \
        __builtin_amdgcn_s_setprio(1);                                          \
        _Pragma("unroll")                                                       \
        for (int kt = 0; kt < 5; ++kt) {                                        \
            acc[0]  = __builtin_amdgcn_mfma_f32_16x16x32_bf16(afrag[0][kt],   bfr[kt],   acc[0],  0, 0, 0); \
            accB[0] = __builtin_amdgcn_mfma_f32_16x16x32_bf16(afrag[0][kt+5], bfr[kt+5], accB[0], 0, 0, 0); \
            acc[1]  = __builtin_amdgcn_mfma_f32_16x16x32_bf16(afrag[1][kt],   bfr[kt],   acc[1],  0, 0, 0); \
            accB[1] = __builtin_amdgcn_mfma_f32_16x16x32_bf16(afrag[1][kt+5], bfr[kt+5], accB[1], 0, 0, 0); \
            if (w4) {                                                           \
                acc[2]  = __builtin_amdgcn_mfma_f32_16x16x32_bf16(afrag[2][kt],   bfr[kt],   acc[2],  0, 0, 0); \
                accB[2] = __builtin_amdgcn_mfma_f32_16x16x32_bf16(afrag[2][kt+5], bfr[kt+5], accB[2], 0, 0, 0); \
            }                                                                   \
        }                                                                       \
        __builtin_amdgcn_s_setprio(0);                                          \
        _Pragma("unroll")                                                       \
        for (int q = 0; q < 3; ++q) {                                           \
            if (!QOK(q)) continue;                                              \
            f32x4 hv;                                                           \
            _Pragma("unroll")                                                   \
            for (int i = 0; i < 4; ++i) {                                       \
                float zn = acc[q][i] + accB[q][i];                              \
                float ex, sg;                                                   \
                asm("v_exp_f32 %0, %1" : "=v"(ex) : "v"(zn));                   \
                asm("v_rcp_f32 %0, %1" : "=v"(sg) : "v"(1.0f + ex));            \
                hv[i] = sg;                                                     \
            }                                                                   \
            unsigned plo, phi;                                                  \
            asm("v_cvt_pk_bf16_f32 %0, %1, %2" : "=v"(plo) : "v"(hv[0]), "v"(hv[1])); \
            asm("v_cvt_pk_bf16_f32 %0, %1, %2" : "=v"(phi) : "v"(hv[2]), "v"(hv[3])); \
            HPME[q].x = plo; HPME[q].y = phi;                                   \
            *(uint2*)((char*)hlds + ((P) ^ 1) * 10240 + ldsoff[q]) = HPME[q];   \
            if (t > 0 && rq[q] < 300)                                           \
                *(uint2*)(sbase + so + rq[q] * 2) = HPOTHER[q];                 \
        }                                                                       \
        asm volatile("s_waitcnt lgkmcnt(0)" ::: "memory");                      \
        __builtin_amdgcn_s_barrier();                                           \
        asm volatile("" ::: "memory");                                          \
    }

__global__ __launch_bounds__(512) void elman_rec_mfma(
    const float* __restrict__ W1, float* __restrict__ buf,
    float* __restrict__ hfinal)
{
    __shared__ unsigned short hlds[2][10 * 64 * 8];
    const int tid = threadIdx.x;
    const int w = tid >> 6, l = tid & 63, lg = l >> 4, ln = l & 15;
    const bool w4 = (w < 4);
    const int bb = blockIdx.x * 16 + ln;

    int rq[3], ldsoff[3];
    #pragma unroll
    for (int q = 0; q < 3; ++q) {
        int tile = w4 ? (3 * w + q) : (12 + 2 * (w - 4) + q);
        int r = tile * 16 + 4 * lg;
        rq[q] = r;
        ldsoff[q] = (((r >> 5) * 64 + ((r >> 3) & 3) * 16 + ln) * 8 + (r & 7)) * 2;
    }

    bf16x8 afrag[3][10];
    #pragma unroll
    for (int q = 0; q < 3; ++q) {
        #pragma unroll
        for (int kt = 0; kt < 10; ++kt) {
            bool qa = (q < 2) || w4;
            int tile = w4 ? (3 * w + q) : (12 + 2 * (w - 4) + q);
            int r = tile * 16 + ln;
            int k0 = kt * 32 + lg * 8;
            uint4 p = load8_cvt_s(W1 + (size_t)r * 600 + 300 + k0,
                                  qa && r < 300, 300 - k0, NL2E);
            union { uint4 u; bf16x8 s; } cv; cv.u = p;
            afrag[q][kt] = cv.s;
        }
    }

    for (int i = tid; i < 10 * 64 * 8; i += 512) hlds[0][i] = 0;

    const char* abase = (const char*)(buf + (size_t)bb * T_ * 300);
    char* sbase = (char*)buf + (size_t)bb * 16 * 76800;

    f32x4 A0[3], A1[3];
    #pragma unroll
    for (int q = 0; q < 3; ++q)
        if (QOK(q)) {
            A0[q] = *(const f32x4*)(abase + rq[q] * 4);
            A1[q] = *(const f32x4*)(abase + 1200 + rq[q] * 4);
        }
    const char* aptr0 = abase + 2400;
    const char* aptr1 = abase + 3600;
    uint2 hpA[3], hpB[3];
    __syncthreads();

    for (int t2 = 0; t2 < T_; t2 += 2) {
        K2_STEP(0, t2,     A0, aptr0, hpA, hpB)
        K2_STEP(1, t2 + 1, A1, aptr1, hpB, hpA)
    }

    {
        const int tt = T_ - 1;
        const size_t so = (size_t)(tt >> 6) * 76800 + (size_t)(tt & 63) * 600;
        #pragma unroll
        for (int q = 0; q < 3; ++q)
            if (QOK(q) && rq[q] < 300) {
                *(uint2*)(sbase + so + rq[q] * 2) = hpB[q];
                f32x4 hv;
                union { float f; unsigned u; } c0, c1, c2, c3;
                c0.u = hpB[q].x << 16; c1.u = hpB[q].x & 0xFFFF0000u;
                c2.u = hpB[q].y << 16; c3.u = hpB[q].y & 0xFFFF0000u;
                hv[0] = c0.f; hv[1] = c1.f; hv[2] = c2.f; hv[3] = c3.f;
                *(f32x4*)(hfinal + bb * 300 + rq[q]) = hv;
            }
    }
}

// ---------------------------------------------------------------------------
// FALLBACK K3: in place over packed-h d_out (one block per 64-row chunk).
// ---------------------------------------------------------------------------
__global__ __launch_bounds__(256) void gemm_out(
    float* __restrict__ buf, const float* __restrict__ W2,
    const float* __restrict__ b2)
{
    __shared__ unsigned short alds[4 * 64 * 8];
    __shared__ unsigned short blds[19 * 64 * 8];
    const int tid = threadIdx.x;
    const int w = tid >> 6, l = tid & 63, lg = l >> 4, ln = l & 15;
    const size_t chunk = blockIdx.x;
    const char* pbase = (const char*)buf + chunk * 76800;

    f32x4 acc[19];
    #pragma unroll
    for (int nt = 0; nt < 19; ++nt) acc[nt] = (f32x4){0.f,0.f,0.f,0.f};

    for (int kt = 0; kt < 10; ++kt) {
        const int kc = kt * 32;
        __syncthreads();
        {
            int row = tid >> 2, kh = tid & 3;
            int k0 = kc + kh * 8;
            const char* p = pbase + row * 600;
            uint2 lo = make_uint2(0u, 0u), hi = make_uint2(0u, 0u);
            int krem = 300 - k0;
            if (krem >= 8)      { lo = *(const uint2*)(p + k0 * 2); hi = *(const uint2*)(p + k0 * 2 + 8); }
            else if (krem >= 4) { lo = *(const uint2*)(p + k0 * 2); }
            uint4 pk; pk.x = lo.x; pk.y = lo.y; pk.z = hi.x; pk.w = hi.y;
            *(uint4*)&alds[(((row >> 4) * 64) + kh * 16 + (row & 15)) * 8] = pk;
        }
        #pragma unroll
        for (int rep = 0; rep < 5; ++rep) {
            int e = tid + rep * 256;
            if (e < 1216) {
                int nn = e >> 2, kh = e & 3;
                int k0 = kc + kh * 8;
                uint4 p = load8_cvt(W2 + (size_t)nn * 300 + k0, nn < 300, 300 - k0);
                *(uint4*)&blds[(((nn >> 4) * 64) + kh * 16 + (nn & 15)) * 8] = p;
            }
        }
        __syncthreads();
        bf16x8 afr = *(const bf16x8*)&alds[(w * 64 + l) * 8];
        #pragma unroll
        for (int nt = 0; nt < 19; ++nt) {
            bf16x8 bfr = *(const bf16x8*)&blds[(nt * 64 + l) * 8];
            acc[nt] = __builtin_amdgcn_mfma_f32_16x16x32_bf16(afr, bfr, acc[nt], 0, 0, 0);
        }
    }

    float* frow = buf + chunk * 19200;
    #pragma unroll
    for (int nt = 0; nt < 19; ++nt) {
        int n = nt * 16 + ln;
        if (n < 300) {
            float bias = b2[n];
            int mr = w * 16 + lg * 4;
            #pragma unroll
            for (int i = 0; i < 4; ++i)
                frow[(mr + i) * 300 + n] = acc[nt][i] + bias;
        }
    }
}

// ---------------------------------------------------------------------------
extern "C" void kernel_launch(void* const* d_in, const int* in_sizes, int n_in,
                              void* d_out, int out_size, void* d_ws, size_t ws_size,
                              hipStream_t stream)
{
    const float* x  = (const float*)d_in[0];
    const float* W1 = (const float*)d_in[1];
    const float* b1 = (const float*)d_in[2];
    const float* W2 = (const float*)d_in[3];
    const float* b2 = (const float*)d_in[4];

    float* out    = (float*)d_out;
    float* hfinal = out + (size_t)HB;

    const size_t HT4 = (size_t)T_ * 75 * 128 * 8;   // 78,643,200 B
    if (ws_size >= HT4 + 2 * 76800) {               // + prefetch overrun slack
        gemm_in_t<<<1024, 256, 0, stream>>>(x, W1, b1, (char*)d_ws);
        elman_rec_ws<<<8, 512, 0, stream>>>(W1, hfinal, (char*)d_ws);
        gemm_out_t<<<1024, 256, 0, stream>>>((const char*)d_ws, W2, b2, out);
    } else {
        gemm_in<<<dim3(1024, 2), 256, 0, stream>>>(x, W1, b1, out);
        elman_rec_mfma<<<8, 512, 0, stream>>>(W1, out, hfinal);
        gemm_out<<<2048, 256, 0, stream>>>(out, W2, b2);
    }
}

// Round 12
// 1149.465 us; speedup vs baseline: 1.8590x; 1.0563x over previous
//
#include <hip/hip_runtime.h>

typedef __attribute__((ext_vector_type(4))) float f32x4;
typedef __attribute__((ext_vector_type(8))) short bf16x8;

#define B_   128
#define T_   1024
#define NROW 131072      // B*T
#define HB   (NROW*300)  // floats in the [B*T][300] matrix
#define NL2E -1.44269504088896340736f   // -log2(e)

__device__ inline unsigned short f2bf(float f) {
    union { float f; unsigned int u; } v; v.f = f;
    unsigned int r = v.u + 0x7FFFu + ((v.u >> 16) & 1u);
    return (unsigned short)(r >> 16);
}

// Load up to 8 consecutive f32 (zero-masked at K=300 boundary), scale, convert
// to bf16, return packed uint4 (8 bf16, fragment j-order = ascending k).
__device__ inline uint4 load8_cvt_s(const float* src, bool rowok, int krem, float scale) {
    f32x4 v0 = {0.f,0.f,0.f,0.f}, v1 = {0.f,0.f,0.f,0.f};
    if (rowok) {
        if (krem >= 8)      { v0 = *(const f32x4*)src; v1 = *(const f32x4*)(src + 4); }
        else if (krem >= 4) { v0 = *(const f32x4*)src; }
    }
    v0 *= scale; v1 *= scale;
    uint4 p;
    p.x = (unsigned)f2bf(v0[0]) | ((unsigned)f2bf(v0[1]) << 16);
    p.y = (unsigned)f2bf(v0[2]) | ((unsigned)f2bf(v0[3]) << 16);
    p.z = (unsigned)f2bf(v1[0]) | ((unsigned)f2bf(v1[1]) << 16);
    p.w = (unsigned)f2bf(v1[2]) | ((unsigned)f2bf(v1[3]) << 16);
    return p;
}

__device__ inline uint4 load8_cvt(const float* src, bool rowok, int krem) {
    return load8_cvt_s(src, rowok, krem, 1.0f);
}

// ---------------------------------------------------------------------------
// K1-T (ws path): A'_T4[t][rg=n/4][b][4 bf16] = -log2e*(x[b,t]·W1x^T + b1),
// packed bf16, time-major into d_ws.
// ---------------------------------------------------------------------------
__global__ __launch_bounds__(256) void gemm_in_t(
    const float* __restrict__ X, const float* __restrict__ W1,
    const float* __restrict__ b1, char* __restrict__ aws)
{
    __shared__ unsigned short wlds[19 * 64 * 8];   // W1x frag-linear (M=n)
    __shared__ unsigned short xlds[8 * 64 * 8];    // x frag-linear (N=b)
    const int tid = threadIdx.x;
    const int w = tid >> 6, l = tid & 63, lg = l >> 4, ln = l & 15;
    const int t = blockIdx.x;

    f32x4 acc[2][19];
    #pragma unroll
    for (int q = 0; q < 2; ++q)
        #pragma unroll
        for (int mt = 0; mt < 19; ++mt) acc[q][mt] = (f32x4){0.f,0.f,0.f,0.f};

    for (int kt = 0; kt < 10; ++kt) {
        const int kc = kt * 32;
        __syncthreads();
        #pragma unroll
        for (int rep = 0; rep < 5; ++rep) {
            int e = tid + rep * 256;
            if (e < 1216) {
                int nn = e >> 2, kh = e & 3;
                int k0 = kc + kh * 8;
                uint4 p = load8_cvt_s(W1 + (size_t)nn * 600 + k0, nn < 300, 300 - k0, NL2E);
                *(uint4*)&wlds[(((nn >> 4) * 64) + kh * 16 + (nn & 15)) * 8] = p;
            }
        }
        #pragma unroll
        for (int rep = 0; rep < 2; ++rep) {
            int e = tid + rep * 256;           // < 512
            int row = e >> 2, kh = e & 3;
            int k0 = kc + kh * 8;
            uint4 p = load8_cvt(X + ((size_t)row * 1024 + t) * 300 + k0, true, 300 - k0);
            *(uint4*)&xlds[(((row >> 4) * 64) + kh * 16 + (row & 15)) * 8] = p;
        }
        __syncthreads();
        bf16x8 wfr[19];
        #pragma unroll
        for (int mt = 0; mt < 19; ++mt) wfr[mt] = *(const bf16x8*)&wlds[(mt * 64 + l) * 8];
        #pragma unroll
        for (int q = 0; q < 2; ++q) {
            bf16x8 xfr = *(const bf16x8*)&xlds[((w * 2 + q) * 64 + l) * 8];
            #pragma unroll
            for (int mt = 0; mt < 19; ++mt)
                acc[q][mt] = __builtin_amdgcn_mfma_f32_16x16x32_bf16(wfr[mt], xfr, acc[q][mt], 0, 0, 0);
        }
    }

    char* tb = aws + (size_t)t * 76800;
    #pragma unroll
    for (int q = 0; q < 2; ++q) {
        int b = (w * 2 + q) * 16 + ln;
        #pragma unroll
        for (int mt = 0; mt < 19; ++mt) {
            int rg = mt * 4 + lg;
            if (rg < 75) {
                f32x4 bias = *(const f32x4*)(b1 + mt * 16 + lg * 4);
                float v0 = acc[q][mt][0] + bias[0] * NL2E;
                float v1 = acc[q][mt][1] + bias[1] * NL2E;
                float v2 = acc[q][mt][2] + bias[2] * NL2E;
                float v3 = acc[q][mt][3] + bias[3] * NL2E;
                unsigned plo, phi;
                asm("v_cvt_pk_bf16_f32 %0, %1, %2" : "=v"(plo) : "v"(v0), "v"(v1));
                asm("v_cvt_pk_bf16_f32 %0, %1, %2" : "=v"(phi) : "v"(v2), "v"(v3));
                uint2 pk; pk.x = plo; pk.y = phi;
                *(uint2*)(tb + (size_t)rg * 1024 + b * 8) = pk;
            }
        }
    }
}

#define QOK(q) ((q) < 2 || w4)

// ---------------------------------------------------------------------------
// K2-WS3: recurrence; A'/h in d_ws time-major (h(t) overwrites A'(t) in place,
// same lane+address, consumed before stored -> race-free). 8 blocks x 512 thr.
// THIS ROUND: per-q MFMA/sigmoid interleave (chains q0+q1 -> sig q0 -> chain
// q2 -> sig q1 -> sig q2) so the VALU sigmoid of one M-group overlaps the
// MFMA pipe time of the next; uniform time pointer (SGPR) + constant per-lane
// voffset for all ws traffic (no per-step 64-bit VGPR pointer arith).
// ---------------------------------------------------------------------------
#define K2_CHAIN(q)                                                             \
    _Pragma("unroll")                                                           \
    for (int kt = 0; kt < 5; ++kt) {                                            \
        acc[q]  = __builtin_amdgcn_mfma_f32_16x16x32_bf16(afrag[q][kt],   bfr[kt],   acc[q],  0, 0, 0); \
        accB[q] = __builtin_amdgcn_mfma_f32_16x16x32_bf16(afrag[q][kt+5], bfr[kt+5], accB[q], 0, 0, 0); \
    }

#define K2_SIG(q, P, HWT, t)                                                    \
    {                                                                           \
        f32x4 hv;                                                               \
        _Pragma("unroll")                                                       \
        for (int i = 0; i < 4; ++i) {                                           \
            float zn = acc[q][i] + accB[q][i];      /* = -z*log2e */            \
            float ex, sg;                                                       \
            asm("v_exp_f32 %0, %1" : "=v"(ex) : "v"(zn));                       \
            asm("v_rcp_f32 %0, %1" : "=v"(sg) : "v"(1.0f + ex));                \
            hv[i] = sg;                                                         \
        }                                                                       \
        unsigned plo, phi;                                                      \
        asm("v_cvt_pk_bf16_f32 %0, %1, %2" : "=v"(plo) : "v"(hv[0]), "v"(hv[1])); \
        asm("v_cvt_pk_bf16_f32 %0, %1, %2" : "=v"(phi) : "v"(hv[2]), "v"(hv[3])); \
        uint2 pk; pk.x = plo; pk.y = phi;                                       \
        *(uint2*)((char*)hlds + ((P) ^ 1) * 10240 + ldsoff[q]) = pk;            \
        if (rq[q] < 300) {                                                      \
            *(uint2*)((HWT) + loff[q]) = pk;    /* h(t) overwrites A'(t) */     \
            if ((t) == T_ - 1)                                                  \
                *(f32x4*)(hfinal + bb * 300 + rq[q]) = hv;                      \
        }                                                                       \
    }

#define K2W_STEP(P, tval, AS, HWT)                                              \
    {                                                                           \
        const int t = (tval);                                                   \
        bf16x8 bfr[10];                                                         \
        _Pragma("unroll")                                                       \
        for (int kt = 0; kt < 10; ++kt)                                         \
            bfr[kt] = *(const bf16x8*)&hlds[P][(kt * 64 + l) * 8];              \
        f32x4 acc[3], accB[3];                                                  \
        _Pragma("unroll")                                                       \
        for (int q = 0; q < 3; ++q) {                                           \
            union { float f; unsigned u; } u0, u1, u2, u3;                      \
            u0.u = AS[q].x << 16; u1.u = AS[q].x & 0xFFFF0000u;                 \
            u2.u = AS[q].y << 16; u3.u = AS[q].y & 0xFFFF0000u;                 \
            acc[q] = (f32x4){u0.f, u1.f, u2.f, u3.f};                           \
            accB[q] = (f32x4){0.f,0.f,0.f,0.f};                                 \
        }                                                                       \
        /* prefetch A'(t+2): uniform base + const lane offset */                \
        _Pragma("unroll")                                                       \
        for (int q = 0; q < 3; ++q)                                             \
            if (QOK(q)) AS[q] = *(const uint2*)((HWT) + 153600 + loff[q]);      \
        __builtin_amdgcn_s_setprio(1);                                          \
        K2_CHAIN(0)                                                             \
        K2_CHAIN(1)                                                             \
        __builtin_amdgcn_s_setprio(0);                                          \
        K2_SIG(0, P, HWT, t)                                                    \
        if (w4) {                                                               \
            __builtin_amdgcn_s_setprio(1);                                      \
            K2_CHAIN(2)                                                         \
            __builtin_amdgcn_s_setprio(0);                                      \
        }                                                                       \
        K2_SIG(1, P, HWT, t)                                                    \
        if (w4) K2_SIG(2, P, HWT, t)                                            \
        HWT += 153600;                                                          \
        asm volatile("s_waitcnt lgkmcnt(0)" ::: "memory");                      \
        __builtin_amdgcn_s_barrier();                                           \
        asm volatile("" ::: "memory");                                          \
    }

__global__ __launch_bounds__(512) void elman_rec_ws(
    const float* __restrict__ W1, float* __restrict__ hfinal,
    char* __restrict__ hws)
{
    __shared__ unsigned short hlds[2][10 * 64 * 8];   // 2 x 10240 B
    const int tid = threadIdx.x;
    const int w = tid >> 6, l = tid & 63, lg = l >> 4, ln = l & 15;
    const bool w4 = (w < 4);
    const int bb = blockIdx.x * 16 + ln;    // this lane's batch (B/C column)

    int rq[3], ldsoff[3], loff[3];
    #pragma unroll
    for (int q = 0; q < 3; ++q) {
        int tile = w4 ? (3 * w + q) : (12 + 2 * (w - 4) + q);
        int r = tile * 16 + 4 * lg;
        rq[q] = r;
        ldsoff[q] = (((r >> 5) * 64 + ((r >> 3) & 3) * 16 + ln) * 8 + (r & 7)) * 2;
        int rgc = r >> 2; if (rgc > 74) rgc = 74;
        loff[q] = rgc * 1024 + bb * 8;      // constant per-lane ws offset
    }

    // W1h A-fragments, scaled by -log2e (rows >=300, k>=300 zeroed)
    bf16x8 afrag[3][10];
    #pragma unroll
    for (int q = 0; q < 3; ++q) {
        #pragma unroll
        for (int kt = 0; kt < 10; ++kt) {
            bool qa = (q < 2) || w4;
            int tile = w4 ? (3 * w + q) : (12 + 2 * (w - 4) + q);
            int r = tile * 16 + ln;
            int k0 = kt * 32 + lg * 8;
            uint4 p = load8_cvt_s(W1 + (size_t)r * 600 + 300 + k0,
                                  qa && r < 300, 300 - k0, NL2E);
            union { uint4 u; bf16x8 s; } cv; cv.u = p;
            afrag[q][kt] = cv.s;
        }
    }

    for (int i = tid; i < 10 * 64 * 8; i += 512) hlds[0][i] = 0;

    // uniform time pointers (per parity), advanced 2 steps per pair
    char* HWT0 = hws;            // even steps t = 0,2,...
    char* HWT1 = hws + 76800;    // odd steps  t = 1,3,...

    uint2 AS0[3], AS1[3];
    #pragma unroll
    for (int q = 0; q < 3; ++q)
        if (QOK(q)) {
            AS0[q] = *(const uint2*)(HWT0 + loff[q]);   // A'(0)
            AS1[q] = *(const uint2*)(HWT1 + loff[q]);   // A'(1)
        }
    __syncthreads();

    for (int t2 = 0; t2 < T_; t2 += 2) {
        K2W_STEP(0, t2,     AS0, HWT0)
        K2W_STEP(1, t2 + 1, AS1, HWT1)
    }
}

// ---------------------------------------------------------------------------
// K3-T: out[b][t][n] = sum_r h_T4[t][r][b]*W2[n][r] + b2[n]. One block per t.
// ---------------------------------------------------------------------------
__global__ __launch_bounds__(256) void gemm_out_t(
    const char* __restrict__ hws, const float* __restrict__ W2,
    const float* __restrict__ b2, float* __restrict__ out)
{
    __shared__ unsigned short ahs[8 * 132 * 4];    // 8448 B
    __shared__ unsigned short blds[19 * 64 * 8];   // 19456 B
    const int tid = threadIdx.x;
    const int w = tid >> 6, l = tid & 63, lg = l >> 4, ln = l & 15;
    const int t = blockIdx.x;
    const char* hbase = hws + (size_t)t * 76800;

    f32x4 acc[2][19];
    #pragma unroll
    for (int q = 0; q < 2; ++q)
        #pragma unroll
        for (int nt = 0; nt < 19; ++nt) acc[q][nt] = (f32x4){0.f,0.f,0.f,0.f};

    for (int kt = 0; kt < 10; ++kt) {
        const int kc = kt * 32;
        __syncthreads();
        #pragma unroll
        for (int it = 0; it < 4; ++it) {
            int e = tid + it * 256;            // < 1024
            int rg = e >> 7, b = e & 127;
            int rgg = kt * 8 + rg;
            uint2 v = make_uint2(0u, 0u);
            if (rgg < 75) v = *(const uint2*)(hbase + (size_t)rgg * 1024 + b * 8);
            *(uint2*)&ahs[(rg * 132 + b) * 4] = v;
        }
        #pragma unroll
        for (int rep = 0; rep < 5; ++rep) {
            int e = tid + rep * 256;
            if (e < 1216) {
                int nn = e >> 2, kh = e & 3;
                int k0 = kc + kh * 8;
                uint4 p = load8_cvt(W2 + (size_t)nn * 300 + k0, nn < 300, 300 - k0);
                *(uint4*)&blds[(((nn >> 4) * 64) + kh * 16 + (nn & 15)) * 8] = p;
            }
        }
        __syncthreads();
        bf16x8 bfr[19];
        #pragma unroll
        for (int nt = 0; nt < 19; ++nt) bfr[nt] = *(const bf16x8*)&blds[(nt * 64 + l) * 8];
        #pragma unroll
        for (int q = 0; q < 2; ++q) {
            int b = (w * 2 + q) * 16 + ln;
            uint2 u0 = *(const uint2*)&ahs[((2 * lg)     * 132 + b) * 4];
            uint2 u1 = *(const uint2*)&ahs[((2 * lg + 1) * 132 + b) * 4];
            union { uint4 u; bf16x8 s; } cv;
            cv.u.x = u0.x; cv.u.y = u0.y; cv.u.z = u1.x; cv.u.w = u1.y;
            bf16x8 afr = cv.s;
            #pragma unroll
            for (int nt = 0; nt < 19; ++nt)
                acc[q][nt] = __builtin_amdgcn_mfma_f32_16x16x32_bf16(afr, bfr[nt], acc[q][nt], 0, 0, 0);
        }
    }

    #pragma unroll
    for (int q = 0; q < 2; ++q)
        #pragma unroll
        for (int nt = 0; nt < 19; ++nt) {
            int n = nt * 16 + ln;
            if (n < 300) {
                float bias = b2[n];
                int b0r = (w * 2 + q) * 16 + lg * 4;
                #pragma unroll
                for (int i = 0; i < 4; ++i)
                    out[((size_t)(b0r + i) * T_ + t) * 300 + n] = acc[q][nt][i] + bias;
            }
        }
}

// ---------------------------------------------------------------------------
// FALLBACK path (small ws): R9 kernels, unchanged.
// ---------------------------------------------------------------------------
__global__ __launch_bounds__(256) void gemm_in(
    const float* __restrict__ X, const float* __restrict__ W1,
    const float* __restrict__ b1, float* __restrict__ A)
{
    __shared__ unsigned short alds[8 * 64 * 8];
    __shared__ unsigned short blds[10 * 64 * 8];
    const int tid = threadIdx.x;
    const int w = tid >> 6, l = tid & 63, lg = l >> 4, ln = l & 15;
    const size_t m0 = (size_t)blockIdx.x * 128;
    const int n0 = blockIdx.y * 160;

    f32x4 acc[2][10];
    #pragma unroll
    for (int q = 0; q < 2; ++q)
        #pragma unroll
        for (int nt = 0; nt < 10; ++nt) acc[q][nt] = (f32x4){0.f,0.f,0.f,0.f};

    for (int kt = 0; kt < 10; ++kt) {
        const int kc = kt * 32;
        __syncthreads();
        #pragma unroll
        for (int rep = 0; rep < 2; ++rep) {
            int e = tid + rep * 256;
            int row = e >> 2, kh = e & 3;
            int k0 = kc + kh * 8;
            uint4 p = load8_cvt(X + (m0 + row) * 300 + k0, true, 300 - k0);
            *(uint4*)&alds[(((row >> 4) * 64) + kh * 16 + (row & 15)) * 8] = p;
        }
        #pragma unroll
        for (int rep = 0; rep < 3; ++rep) {
            int e = tid + rep * 256;
            if (e < 640) {
                int nn = e >> 2, kh = e & 3;
                int n = n0 + nn;
                int k0 = kc + kh * 8;
                uint4 p = load8_cvt(W1 + (size_t)n * 600 + k0, n < 300, 300 - k0);
                *(uint4*)&blds[(((nn >> 4) * 64) + kh * 16 + (nn & 15)) * 8] = p;
            }
        }
        __syncthreads();
        bf16x8 bfr[10];
        #pragma unroll
        for (int nt = 0; nt < 10; ++nt) bfr[nt] = *(const bf16x8*)&blds[(nt * 64 + l) * 8];
        #pragma unroll
        for (int q = 0; q < 2; ++q) {
            bf16x8 afr = *(const bf16x8*)&alds[((w * 2 + q) * 64 + l) * 8];
            #pragma unroll
            for (int nt = 0; nt < 10; ++nt)
                acc[q][nt] = __builtin_amdgcn_mfma_f32_16x16x32_bf16(afr, bfr[nt], acc[q][nt], 0, 0, 0);
        }
    }

    #pragma unroll
    for (int q = 0; q < 2; ++q)
        #pragma unroll
        for (int nt = 0; nt < 10; ++nt) {
            int n = n0 + nt * 16 + ln;
            if (n < 300) {
                float bias = b1[n];
                size_t mr = m0 + (w * 2 + q) * 16 + lg * 4;
                #pragma unroll
                for (int i = 0; i < 4; ++i)
                    A[(mr + i) * 300 + n] = (acc[q][nt][i] + bias) * NL2E;
            }
        }
}

#define K2_STEP(P, tval, ASLOT, APTR, HPME, HPOTHER)                            \
    {                                                                           \
        const int t = (tval);                                                   \
        const int tt = t - 1;                                                   \
        const size_t so = (size_t)(tt >> 6) * 76800 + (size_t)(tt & 63) * 600;  \
        bf16x8 bfr[10];                                                         \
        _Pragma("unroll")                                                       \
        for (int kt = 0; kt < 10; ++kt)                                         \
            bfr[kt] = *(const bf16x8*)&hlds[P][(kt * 64 + l) * 8];              \
        f32x4 acc[3], accB[3];                                                  \
        _Pragma("unroll")                                                       \
        for (int q = 0; q < 3; ++q) {                                           \
            acc[q] = QOK(q) ? ASLOT[q] : (f32x4){0.f,0.f,0.f,0.f};              \
            accB[q] = (f32x4){0.f,0.f,0.f,0.f};                                 \
        }                                                                       \
        _Pragma("unroll")                                                       \
        for (int q = 0; q < 3; ++q)                                             \
            if (QOK(q)) ASLOT[q] = *(const f32x4*)(APTR + rq[q] * 4);           \
        APTR += 2400;                                                           \
        __builtin_amdgcn_s_setprio(1);                                          \
        _Pragma("unroll")                                                       \
        for (int kt = 0; kt < 5; ++kt) {                                        \
            acc[0]  = __builtin_amdgcn_mfma_f32_16x16x32_bf16(afrag[0][kt],   bfr[kt],   acc[0],  0, 0, 0); \
            accB[0] = __builtin_amdgcn_mfma_f32_16x16x32_bf16(afrag[0][kt+5], bfr[kt+5], accB[0], 0, 0, 0); \
            acc[1]  = __builtin_amdgcn_mfma_f32_16x16x32_bf16(afrag[1][kt],   bfr[kt],   acc[1],  0, 0, 0); \
            accB[1] = __builtin_amdgcn_mfma_f32_16x16x32_bf16(afrag[1][kt+5], bfr[kt+5], accB[1], 0, 0, 0); \
            if (w4) {                                                           \
                acc[2]  = __builtin_amdgcn_mfma_f32_16x16x32_bf16(afrag[2][kt],   bfr[kt],   acc[2],  0, 0, 0); \
                accB[2] = __builtin_amdgcn_mfma_f32_16x16x32_bf16(afrag[2][kt+5], bfr[kt+5], accB[2], 0, 0, 0); \
            }                                                                   \
        }                                                                       \
        __builtin_amdgcn_s_setprio(0);                                          \
        _Pragma("unroll")                                                       \
        for (int q = 0; q < 3; ++q) {                                           \
            if (!QOK(q)) continue;                                              \
            f32x4 hv;                                                           \
            _Pragma("unroll")                                                   \
            for (int i = 0; i < 4; ++i) {                                       \
                float zn = acc[q][i] + accB[q][i];                              \
                float ex, sg;                                                   \
                asm("v_exp_f32 %0, %1" : "=v"(ex) : "v"(zn));                   \
                asm("v_rcp_f32 %0, %1" : "=v"(sg) : "v"(1.0f + ex));            \
                hv[i] = sg;                                                     \
            }                                                                   \
            unsigned plo, phi;                                                  \
            asm("v_cvt_pk_bf16_f32 %0, %1, %2" : "=v"(plo) : "v"(hv[0]), "v"(hv[1])); \
            asm("v_cvt_pk_bf16_f32 %0, %1, %2" : "=v"(phi) : "v"(hv[2]), "v"(hv[3])); \
            HPME[q].x = plo; HPME[q].y = phi;                                   \
            *(uint2*)((char*)hlds + ((P) ^ 1) * 10240 + ldsoff[q]) = HPME[q];   \
            if (t > 0 && rq[q] < 300)                                           \
                *(uint2*)(sbase + so + rq[q] * 2) = HPOTHER[q];                 \
        }                                                                       \
        asm volatile("s_waitcnt lgkmcnt(0)" ::: "memory");                      \
        __builtin_amdgcn_s_barrier();                                           \
        asm volatile("" ::: "memory");                                          \
    }

__global__ __launch_bounds__(512) void elman_rec_mfma(
    const float* __restrict__ W1, float* __restrict__ buf,
    float* __restrict__ hfinal)
{
    __shared__ unsigned short hlds[2][10 * 64 * 8];
    const int tid = threadIdx.x;
    const int w = tid >> 6, l = tid & 63, lg = l >> 4, ln = l & 15;
    const bool w4 = (w < 4);
    const int bb = blockIdx.x * 16 + ln;

    int rq[3], ldsoff[3];
    #pragma unroll
    for (int q = 0; q < 3; ++q) {
        int tile = w4 ? (3 * w + q) : (12 + 2 * (w - 4) + q);
        int r = tile * 16 + 4 * lg;
        rq[q] = r;
        ldsoff[q] = (((r >> 5) * 64 + ((r >> 3) & 3) * 16 + ln) * 8 + (r & 7)) * 2;
    }

    bf16x8 afrag[3][10];
    #pragma unroll
    for (int q = 0; q < 3; ++q) {
        #pragma unroll
        for (int kt = 0; kt < 10; ++kt) {
            bool qa = (q < 2) || w4;
            int tile = w4 ? (3 * w + q) : (12 + 2 * (w - 4) + q);
            int r = tile * 16 + ln;
            int k0 = kt * 32 + lg * 8;
            uint4 p = load8_cvt_s(W1 + (size_t)r * 600 + 300 + k0,
                                  qa && r < 300, 300 - k0, NL2E);
            union { uint4 u; bf16x8 s; } cv; cv.u = p;
            afrag[q][kt] = cv.s;
        }
    }

    for (int i = tid; i < 10 * 64 * 8; i += 512) hlds[0][i] = 0;

    const char* abase = (const char*)(buf + (size_t)bb * T_ * 300);
    char* sbase = (char*)buf + (size_t)bb * 16 * 76800;

    f32x4 A0[3], A1[3];
    #pragma unroll
    for (int q = 0; q < 3; ++q)
        if (QOK(q)) {
            A0[q] = *(const f32x4*)(abase + rq[q] * 4);
            A1[q] = *(const f32x4*)(abase + 1200 + rq[q] * 4);
        }
    const char* aptr0 = abase + 2400;
    const char* aptr1 = abase + 3600;
    uint2 hpA[3], hpB[3];
    __syncthreads();

    for (int t2 = 0; t2 < T_; t2 += 2) {
        K2_STEP(0, t2,     A0, aptr0, hpA, hpB)
        K2_STEP(1, t2 + 1, A1, aptr1, hpB, hpA)
    }

    {
        const int tt = T_ - 1;
        const size_t so = (size_t)(tt >> 6) * 76800 + (size_t)(tt & 63) * 600;
        #pragma unroll
        for (int q = 0; q < 3; ++q)
            if (QOK(q) && rq[q] < 300) {
                *(uint2*)(sbase + so + rq[q] * 2) = hpB[q];
                f32x4 hv;
                union { float f; unsigned u; } c0, c1, c2, c3;
                c0.u = hpB[q].x << 16; c1.u = hpB[q].x & 0xFFFF0000u;
                c2.u = hpB[q].y << 16; c3.u = hpB[q].y & 0xFFFF0000u;
                hv[0] = c0.f; hv[1] = c1.f; hv[2] = c2.f; hv[3] = c3.f;
                *(f32x4*)(hfinal + bb * 300 + rq[q]) = hv;
            }
    }
}

__global__ __launch_bounds__(256) void gemm_out(
    float* __restrict__ buf, const float* __restrict__ W2,
    const float* __restrict__ b2)
{
    __shared__ unsigned short alds[4 * 64 * 8];
    __shared__ unsigned short blds[19 * 64 * 8];
    const int tid = threadIdx.x;
    const int w = tid >> 6, l = tid & 63, lg = l >> 4, ln = l & 15;
    const size_t chunk = blockIdx.x;
    const char* pbase = (const char*)buf + chunk * 76800;

    f32x4 acc[19];
    #pragma unroll
    for (int nt = 0; nt < 19; ++nt) acc[nt] = (f32x4){0.f,0.f,0.f,0.f};

    for (int kt = 0; kt < 10; ++kt) {
        const int kc = kt * 32;
        __syncthreads();
        {
            int row = tid >> 2, kh = tid & 3;
            int k0 = kc + kh * 8;
            const char* p = pbase + row * 600;
            uint2 lo = make_uint2(0u, 0u), hi = make_uint2(0u, 0u);
            int krem = 300 - k0;
            if (krem >= 8)      { lo = *(const uint2*)(p + k0 * 2); hi = *(const uint2*)(p + k0 * 2 + 8); }
            else if (krem >= 4) { lo = *(const uint2*)(p + k0 * 2); }
            uint4 pk; pk.x = lo.x; pk.y = lo.y; pk.z = hi.x; pk.w = hi.y;
            *(uint4*)&alds[(((row >> 4) * 64) + kh * 16 + (row & 15)) * 8] = pk;
        }
        #pragma unroll
        for (int rep = 0; rep < 5; ++rep) {
            int e = tid + rep * 256;
            if (e < 1216) {
                int nn = e >> 2, kh = e & 3;
                int k0 = kc + kh * 8;
                uint4 p = load8_cvt(W2 + (size_t)nn * 300 + k0, nn < 300, 300 - k0);
                *(uint4*)&blds[(((nn >> 4) * 64) + kh * 16 + (nn & 15)) * 8] = p;
            }
        }
        __syncthreads();
        bf16x8 afr = *(const bf16x8*)&alds[(w * 64 + l) * 8];
        #pragma unroll
        for (int nt = 0; nt < 19; ++nt) {
            bf16x8 bfr = *(const bf16x8*)&blds[(nt * 64 + l) * 8];
            acc[nt] = __builtin_amdgcn_mfma_f32_16x16x32_bf16(afr, bfr, acc[nt], 0, 0, 0);
        }
    }

    float* frow = buf + chunk * 19200;
    #pragma unroll
    for (int nt = 0; nt < 19; ++nt) {
        int n = nt * 16 + ln;
        if (n < 300) {
            float bias = b2[n];
            int mr = w * 16 + lg * 4;
            #pragma unroll
            for (int i = 0; i < 4; ++i)
                frow[(mr + i) * 300 + n] = acc[nt][i] + bias;
        }
    }
}

// ---------------------------------------------------------------------------
extern "C" void kernel_launch(void* const* d_in, const int* in_sizes, int n_in,
                              void* d_out, int out_size, void* d_ws, size_t ws_size,
                              hipStream_t stream)
{
    const float* x  = (const float*)d_in[0];
    const float* W1 = (const float*)d_in[1];
    const float* b1 = (const float*)d_in[2];
    const float* W2 = (const float*)d_in[3];
    const float* b2 = (const float*)d_in[4];

    float* out    = (float*)d_out;
    float* hfinal = out + (size_t)HB;

    const size_t HT4 = (size_t)T_ * 75 * 128 * 8;   // 78,643,200 B
    if (ws_size >= HT4 + 2 * 76800) {               // + prefetch overrun slack
        gemm_in_t<<<1024, 256, 0, stream>>>(x, W1, b1, (char*)d_ws);
        elman_rec_ws<<<8, 512, 0, stream>>>(W1, hfinal, (char*)d_ws);
        gemm_out_t<<<1024, 256, 0, stream>>>((const char*)d_ws, W2, b2, out);
    } else {
        gemm_in<<<dim3(1024, 2), 256, 0, stream>>>(x, W1, b1, out);
        elman_rec_mfma<<<8, 512, 0, stream>>>(W1, out, hfinal);
        gemm_out<<<2048, 256, 0, stream>>>(out, W2, b2);
    }
}

// Round 13
// 992.889 us; speedup vs baseline: 2.1521x; 1.1577x over previous
//
#include <hip/hip_runtime.h>

typedef __attribute__((ext_vector_type(4))) float f32x4;
typedef __attribute__((ext_vector_type(8))) short bf16x8;

#define B_   128
#define T_   1024
#define NROW 131072      // B*T
#define HB   (NROW*300)  // floats in the [B*T][300] matrix
#define NL2E -1.44269504088896340736f   // -log2(e)

__device__ inline unsigned short f2bf(float f) {
    union { float f; unsigned int u; } v; v.f = f;
    unsigned int r = v.u + 0x7FFFu + ((v.u >> 16) & 1u);
    return (unsigned short)(r >> 16);
}

// Load up to 8 consecutive f32 (zero-masked at K=300 boundary), scale, convert
// to bf16, return packed uint4 (8 bf16, fragment j-order = ascending k).
__device__ inline uint4 load8_cvt_s(const float* src, bool rowok, int krem, float scale) {
    f32x4 v0 = {0.f,0.f,0.f,0.f}, v1 = {0.f,0.f,0.f,0.f};
    if (rowok) {
        if (krem >= 8)      { v0 = *(const f32x4*)src; v1 = *(const f32x4*)(src + 4); }
        else if (krem >= 4) { v0 = *(const f32x4*)src; }
    }
    v0 *= scale; v1 *= scale;
    uint4 p;
    p.x = (unsigned)f2bf(v0[0]) | ((unsigned)f2bf(v0[1]) << 16);
    p.y = (unsigned)f2bf(v0[2]) | ((unsigned)f2bf(v0[3]) << 16);
    p.z = (unsigned)f2bf(v1[0]) | ((unsigned)f2bf(v1[1]) << 16);
    p.w = (unsigned)f2bf(v1[2]) | ((unsigned)f2bf(v1[3]) << 16);
    return p;
}

__device__ inline uint4 load8_cvt(const float* src, bool rowok, int krem) {
    return load8_cvt_s(src, rowok, krem, 1.0f);
}

// ---------------------------------------------------------------------------
// K1-T2 (ws path): A'_T4[t][rg=n/4][b][4 bf16] = -log2e*(x[b,t]·W1x^T + b1),
// packed bf16, time-major into d_ws. TWO t per block (grid 512, 512 thr):
// waves 0-3 own t0, waves 4-7 own t0+1; W1x tile staged ONCE per kt for both
// (staging work + f2bf VALU per t halved; W1 L2 reads halved).
// ---------------------------------------------------------------------------
__global__ __launch_bounds__(512) void gemm_in_t2(
    const float* __restrict__ X, const float* __restrict__ W1,
    const float* __restrict__ b1, char* __restrict__ aws)
{
    __shared__ unsigned short wlds[19 * 64 * 8];      // 19456 B (shared by all)
    __shared__ unsigned short xlds[2][8 * 64 * 8];    // 2 x 8192 B (per t-half)
    const int tid = threadIdx.x;
    const int w = tid >> 6, l = tid & 63, lg = l >> 4, ln = l & 15;
    const int th = w >> 2, wb = w & 3;                // t-half, b-quarter
    const int t = blockIdx.x * 2 + th;

    f32x4 acc[2][19];
    #pragma unroll
    for (int q = 0; q < 2; ++q)
        #pragma unroll
        for (int mt = 0; mt < 19; ++mt) acc[q][mt] = (f32x4){0.f,0.f,0.f,0.f};

    for (int kt = 0; kt < 10; ++kt) {
        const int kc = kt * 32;
        __syncthreads();
        // stage W1x tile once: 1216 units over 512 threads
        #pragma unroll
        for (int rep = 0; rep < 3; ++rep) {
            int e = tid + rep * 512;
            if (e < 1216) {
                int nn = e >> 2, kh = e & 3;
                int k0 = kc + kh * 8;
                uint4 p = load8_cvt_s(W1 + (size_t)nn * 600 + k0, nn < 300, 300 - k0, NL2E);
                *(uint4*)&wlds[(((nn >> 4) * 64) + kh * 16 + (nn & 15)) * 8] = p;
            }
        }
        // stage x tiles for both t: 512 units each
        #pragma unroll
        for (int tt = 0; tt < 2; ++tt) {
            int e = tid;                       // 512 units: 128 rows x 4 kh
            int row = e >> 2, kh = e & 3;
            int k0 = kc + kh * 8;
            uint4 p = load8_cvt(X + ((size_t)row * 1024 + blockIdx.x * 2 + tt) * 300 + k0,
                                true, 300 - k0);
            *(uint4*)&xlds[tt][(((row >> 4) * 64) + kh * 16 + (row & 15)) * 8] = p;
        }
        __syncthreads();
        bf16x8 wfr[19];
        #pragma unroll
        for (int mt = 0; mt < 19; ++mt) wfr[mt] = *(const bf16x8*)&wlds[(mt * 64 + l) * 8];
        #pragma unroll
        for (int q = 0; q < 2; ++q) {
            bf16x8 xfr = *(const bf16x8*)&xlds[th][((wb * 2 + q) * 64 + l) * 8];
            #pragma unroll
            for (int mt = 0; mt < 19; ++mt)
                acc[q][mt] = __builtin_amdgcn_mfma_f32_16x16x32_bf16(wfr[mt], xfr, acc[q][mt], 0, 0, 0);
        }
    }

    char* tb = aws + (size_t)t * 76800;
    #pragma unroll
    for (int q = 0; q < 2; ++q) {
        int b = (wb * 2 + q) * 16 + ln;
        #pragma unroll
        for (int mt = 0; mt < 19; ++mt) {
            int rg = mt * 4 + lg;
            if (rg < 75) {
                f32x4 bias = *(const f32x4*)(b1 + mt * 16 + lg * 4);
                float v0 = acc[q][mt][0] + bias[0] * NL2E;
                float v1 = acc[q][mt][1] + bias[1] * NL2E;
                float v2 = acc[q][mt][2] + bias[2] * NL2E;
                float v3 = acc[q][mt][3] + bias[3] * NL2E;
                unsigned plo, phi;
                asm("v_cvt_pk_bf16_f32 %0, %1, %2" : "=v"(plo) : "v"(v0), "v"(v1));
                asm("v_cvt_pk_bf16_f32 %0, %1, %2" : "=v"(phi) : "v"(v2), "v"(v3));
                uint2 pk; pk.x = plo; pk.y = phi;
                *(uint2*)(tb + (size_t)rg * 1024 + b * 8) = pk;
            }
        }
    }
}

#define QOK(q) ((q) < 2 || w4)

// ---------------------------------------------------------------------------
// K2-WS3 (unchanged from R12 best): recurrence; A'/h in d_ws time-major
// (h(t) overwrites A'(t) in place; race-free). 8 blocks x 512 thr. Per-q
// MFMA/sigmoid interleave; uniform time pointer + constant lane offsets;
// exp2 sigmoid; one lgkmcnt(0)+s_barrier per step.
// ---------------------------------------------------------------------------
#define K2_CHAIN(q)                                                             \
    _Pragma("unroll")                                                           \
    for (int kt = 0; kt < 5; ++kt) {                                            \
        acc[q]  = __builtin_amdgcn_mfma_f32_16x16x32_bf16(afrag[q][kt],   bfr[kt],   acc[q],  0, 0, 0); \
        accB[q] = __builtin_amdgcn_mfma_f32_16x16x32_bf16(afrag[q][kt+5], bfr[kt+5], accB[q], 0, 0, 0); \
    }

#define K2_SIG(q, P, HWT, t)                                                    \
    {                                                                           \
        f32x4 hv;                                                               \
        _Pragma("unroll")                                                       \
        for (int i = 0; i < 4; ++i) {                                           \
            float zn = acc[q][i] + accB[q][i];      /* = -z*log2e */            \
            float ex, sg;                                                       \
            asm("v_exp_f32 %0, %1" : "=v"(ex) : "v"(zn));                       \
            asm("v_rcp_f32 %0, %1" : "=v"(sg) : "v"(1.0f + ex));                \
            hv[i] = sg;                                                         \
        }                                                                       \
        unsigned plo, phi;                                                      \
        asm("v_cvt_pk_bf16_f32 %0, %1, %2" : "=v"(plo) : "v"(hv[0]), "v"(hv[1])); \
        asm("v_cvt_pk_bf16_f32 %0, %1, %2" : "=v"(phi) : "v"(hv[2]), "v"(hv[3])); \
        uint2 pk; pk.x = plo; pk.y = phi;                                       \
        *(uint2*)((char*)hlds + ((P) ^ 1) * 10240 + ldsoff[q]) = pk;            \
        if (rq[q] < 300) {                                                      \
            *(uint2*)((HWT) + loff[q]) = pk;    /* h(t) overwrites A'(t) */     \
            if ((t) == T_ - 1)                                                  \
                *(f32x4*)(hfinal + bb * 300 + rq[q]) = hv;                      \
        }                                                                       \
    }

#define K2W_STEP(P, tval, AS, HWT)                                              \
    {                                                                           \
        const int t = (tval);                                                   \
        bf16x8 bfr[10];                                                         \
        _Pragma("unroll")                                                       \
        for (int kt = 0; kt < 10; ++kt)                                         \
            bfr[kt] = *(const bf16x8*)&hlds[P][(kt * 64 + l) * 8];              \
        f32x4 acc[3], accB[3];                                                  \
        _Pragma("unroll")                                                       \
        for (int q = 0; q < 3; ++q) {                                           \
            union { float f; unsigned u; } u0, u1, u2, u3;                      \
            u0.u = AS[q].x << 16; u1.u = AS[q].x & 0xFFFF0000u;                 \
            u2.u = AS[q].y << 16; u3.u = AS[q].y & 0xFFFF0000u;                 \
            acc[q] = (f32x4){u0.f, u1.f, u2.f, u3.f};                           \
            accB[q] = (f32x4){0.f,0.f,0.f,0.f};                                 \
        }                                                                       \
        /* prefetch A'(t+2): uniform base + const lane offset */                \
        _Pragma("unroll")                                                       \
        for (int q = 0; q < 3; ++q)                                             \
            if (QOK(q)) AS[q] = *(const uint2*)((HWT) + 153600 + loff[q]);      \
        __builtin_amdgcn_s_setprio(1);                                          \
        K2_CHAIN(0)                                                             \
        K2_CHAIN(1)                                                             \
        __builtin_amdgcn_s_setprio(0);                                          \
        K2_SIG(0, P, HWT, t)                                                    \
        if (w4) {                                                               \
            __builtin_amdgcn_s_setprio(1);                                      \
            K2_CHAIN(2)                                                         \
            __builtin_amdgcn_s_setprio(0);                                      \
        }                                                                       \
        K2_SIG(1, P, HWT, t)                                                    \
        if (w4) K2_SIG(2, P, HWT, t)                                            \
        HWT += 153600;                                                          \
        asm volatile("s_waitcnt lgkmcnt(0)" ::: "memory");                      \
        __builtin_amdgcn_s_barrier();                                           \
        asm volatile("" ::: "memory");                                          \
    }

__global__ __launch_bounds__(512) void elman_rec_ws(
    const float* __restrict__ W1, float* __restrict__ hfinal,
    char* __restrict__ hws)
{
    __shared__ unsigned short hlds[2][10 * 64 * 8];   // 2 x 10240 B
    const int tid = threadIdx.x;
    const int w = tid >> 6, l = tid & 63, lg = l >> 4, ln = l & 15;
    const bool w4 = (w < 4);
    const int bb = blockIdx.x * 16 + ln;    // this lane's batch (B/C column)

    int rq[3], ldsoff[3], loff[3];
    #pragma unroll
    for (int q = 0; q < 3; ++q) {
        int tile = w4 ? (3 * w + q) : (12 + 2 * (w - 4) + q);
        int r = tile * 16 + 4 * lg;
        rq[q] = r;
        ldsoff[q] = (((r >> 5) * 64 + ((r >> 3) & 3) * 16 + ln) * 8 + (r & 7)) * 2;
        int rgc = r >> 2; if (rgc > 74) rgc = 74;
        loff[q] = rgc * 1024 + bb * 8;      // constant per-lane ws offset
    }

    // W1h A-fragments, scaled by -log2e (rows >=300, k>=300 zeroed)
    bf16x8 afrag[3][10];
    #pragma unroll
    for (int q = 0; q < 3; ++q) {
        #pragma unroll
        for (int kt = 0; kt < 10; ++kt) {
            bool qa = (q < 2) || w4;
            int tile = w4 ? (3 * w + q) : (12 + 2 * (w - 4) + q);
            int r = tile * 16 + ln;
            int k0 = kt * 32 + lg * 8;
            uint4 p = load8_cvt_s(W1 + (size_t)r * 600 + 300 + k0,
                                  qa && r < 300, 300 - k0, NL2E);
            union { uint4 u; bf16x8 s; } cv; cv.u = p;
            afrag[q][kt] = cv.s;
        }
    }

    for (int i = tid; i < 10 * 64 * 8; i += 512) hlds[0][i] = 0;

    // uniform time pointers (per parity), advanced 2 steps per pair
    char* HWT0 = hws;            // even steps t = 0,2,...
    char* HWT1 = hws + 76800;    // odd steps  t = 1,3,...

    uint2 AS0[3], AS1[3];
    #pragma unroll
    for (int q = 0; q < 3; ++q)
        if (QOK(q)) {
            AS0[q] = *(const uint2*)(HWT0 + loff[q]);   // A'(0)
            AS1[q] = *(const uint2*)(HWT1 + loff[q]);   // A'(1)
        }
    __syncthreads();

    for (int t2 = 0; t2 < T_; t2 += 2) {
        K2W_STEP(0, t2,     AS0, HWT0)
        K2W_STEP(1, t2 + 1, AS1, HWT1)
    }
}

// ---------------------------------------------------------------------------
// K3-T2: out[b][t][n] = sum_r h_T4[t][r][b]*W2[n][r] + b2[n]. TWO t per block
// (grid 512, 512 thr): waves 0-3 own t0, waves 4-7 own t0+1; W2 tile staged
// once per kt for both t's.
// ---------------------------------------------------------------------------
__global__ __launch_bounds__(512) void gemm_out_t2(
    const char* __restrict__ hws, const float* __restrict__ W2,
    const float* __restrict__ b2, float* __restrict__ out)
{
    __shared__ unsigned short ahs[2][8 * 132 * 4];    // 2 x 8448 B
    __shared__ unsigned short blds[19 * 64 * 8];      // 19456 B
    const int tid = threadIdx.x;
    const int w = tid >> 6, l = tid & 63, lg = l >> 4, ln = l & 15;
    const int th = w >> 2, wb = w & 3;
    const int t = blockIdx.x * 2 + th;

    f32x4 acc[2][19];
    #pragma unroll
    for (int q = 0; q < 2; ++q)
        #pragma unroll
        for (int nt = 0; nt < 19; ++nt) acc[q][nt] = (f32x4){0.f,0.f,0.f,0.f};

    for (int kt = 0; kt < 10; ++kt) {
        const int kc = kt * 32;
        __syncthreads();
        // stage h for both t: rg-chunk kt*8..+7 x 128 b, 1024 units each
        #pragma unroll
        for (int tt = 0; tt < 2; ++tt) {
            const char* hbase = hws + (size_t)(blockIdx.x * 2 + tt) * 76800;
            #pragma unroll
            for (int it = 0; it < 2; ++it) {
                int e = tid + it * 512;            // < 1024
                int rg = e >> 7, b = e & 127;
                int rgg = kt * 8 + rg;
                uint2 v = make_uint2(0u, 0u);
                if (rgg < 75) v = *(const uint2*)(hbase + (size_t)rgg * 1024 + b * 8);
                *(uint2*)&ahs[tt][(rg * 132 + b) * 4] = v;
            }
        }
        // stage W2 tile once: 1216 units
        #pragma unroll
        for (int rep = 0; rep < 3; ++rep) {
            int e = tid + rep * 512;
            if (e < 1216) {
                int nn = e >> 2, kh = e & 3;
                int k0 = kc + kh * 8;
                uint4 p = load8_cvt(W2 + (size_t)nn * 300 + k0, nn < 300, 300 - k0);
                *(uint4*)&blds[(((nn >> 4) * 64) + kh * 16 + (nn & 15)) * 8] = p;
            }
        }
        __syncthreads();
        bf16x8 bfr[19];
        #pragma unroll
        for (int nt = 0; nt < 19; ++nt) bfr[nt] = *(const bf16x8*)&blds[(nt * 64 + l) * 8];
        #pragma unroll
        for (int q = 0; q < 2; ++q) {
            int b = (wb * 2 + q) * 16 + ln;
            uint2 u0 = *(const uint2*)&ahs[th][((2 * lg)     * 132 + b) * 4];
            uint2 u1 = *(const uint2*)&ahs[th][((2 * lg + 1) * 132 + b) * 4];
            union { uint4 u; bf16x8 s; } cv;
            cv.u.x = u0.x; cv.u.y = u0.y; cv.u.z = u1.x; cv.u.w = u1.y;
            bf16x8 afr = cv.s;
            #pragma unroll
            for (int nt = 0; nt < 19; ++nt)
                acc[q][nt] = __builtin_amdgcn_mfma_f32_16x16x32_bf16(afr, bfr[nt], acc[q][nt], 0, 0, 0);
        }
    }

    #pragma unroll
    for (int q = 0; q < 2; ++q)
        #pragma unroll
        for (int nt = 0; nt < 19; ++nt) {
            int n = nt * 16 + ln;
            if (n < 300) {
                float bias = b2[n];
                int b0r = (wb * 2 + q) * 16 + lg * 4;
                #pragma unroll
                for (int i = 0; i < 4; ++i)
                    out[((size_t)(b0r + i) * T_ + t) * 300 + n] = acc[q][nt][i] + bias;
            }
        }
}

// ---------------------------------------------------------------------------
// FALLBACK path (small ws): R9 kernels, unchanged.
// ---------------------------------------------------------------------------
__global__ __launch_bounds__(256) void gemm_in(
    const float* __restrict__ X, const float* __restrict__ W1,
    const float* __restrict__ b1, float* __restrict__ A)
{
    __shared__ unsigned short alds[8 * 64 * 8];
    __shared__ unsigned short blds[10 * 64 * 8];
    const int tid = threadIdx.x;
    const int w = tid >> 6, l = tid & 63, lg = l >> 4, ln = l & 15;
    const size_t m0 = (size_t)blockIdx.x * 128;
    const int n0 = blockIdx.y * 160;

    f32x4 acc[2][10];
    #pragma unroll
    for (int q = 0; q < 2; ++q)
        #pragma unroll
        for (int nt = 0; nt < 10; ++nt) acc[q][nt] = (f32x4){0.f,0.f,0.f,0.f};

    for (int kt = 0; kt < 10; ++kt) {
        const int kc = kt * 32;
        __syncthreads();
        #pragma unroll
        for (int rep = 0; rep < 2; ++rep) {
            int e = tid + rep * 256;
            int row = e >> 2, kh = e & 3;
            int k0 = kc + kh * 8;
            uint4 p = load8_cvt(X + (m0 + row) * 300 + k0, true, 300 - k0);
            *(uint4*)&alds[(((row >> 4) * 64) + kh * 16 + (row & 15)) * 8] = p;
        }
        #pragma unroll
        for (int rep = 0; rep < 3; ++rep) {
            int e = tid + rep * 256;
            if (e < 640) {
                int nn = e >> 2, kh = e & 3;
                int n = n0 + nn;
                int k0 = kc + kh * 8;
                uint4 p = load8_cvt(W1 + (size_t)n * 600 + k0, n < 300, 300 - k0);
                *(uint4*)&blds[(((nn >> 4) * 64) + kh * 16 + (nn & 15)) * 8] = p;
            }
        }
        __syncthreads();
        bf16x8 bfr[10];
        #pragma unroll
        for (int nt = 0; nt < 10; ++nt) bfr[nt] = *(const bf16x8*)&blds[(nt * 64 + l) * 8];
        #pragma unroll
        for (int q = 0; q < 2; ++q) {
            bf16x8 afr = *(const bf16x8*)&alds[((w * 2 + q) * 64 + l) * 8];
            #pragma unroll
            for (int nt = 0; nt < 10; ++nt)
                acc[q][nt] = __builtin_amdgcn_mfma_f32_16x16x32_bf16(afr, bfr[nt], acc[q][nt], 0, 0, 0);
        }
    }

    #pragma unroll
    for (int q = 0; q < 2; ++q)
        #pragma unroll
        for (int nt = 0; nt < 10; ++nt) {
            int n = n0 + nt * 16 + ln;
            if (n < 300) {
                float bias = b1[n];
                size_t mr = m0 + (w * 2 + q) * 16 + lg * 4;
                #pragma unroll
                for (int i = 0; i < 4; ++i)
                    A[(mr + i) * 300 + n] = (acc[q][nt][i] + bias) * NL2E;
            }
        }
}

#define K2_STEP(P, tval, ASLOT, APTR, HPME, HPOTHER)                            \
    {                                                                           \
        const int t = (tval);                                                   \
        const int tt = t - 1;                                                   \
        const size_t so = (size_t)(tt >> 6) * 76800 + (size_t)(tt & 63) * 600;  \
        bf16x8 bfr[10];                                                         \
        _Pragma("unroll")                                                       \
        for (int kt = 0; kt < 10; ++kt)                                         \
            bfr[kt] = *(const bf16x8*)&hlds[P][(kt * 64 + l) * 8];              \
        f32x4 acc[3], accB[3];                                                  \
        _Pragma("unroll")                                                       \
        for (int q = 0; q < 3; ++q) {                                           \
            acc[q] = QOK(q) ? ASLOT[q] : (f32x4){0.f,0.f,0.f,0.f};              \
            accB[q] = (f32x4){0.f,0.f,0.f,0.f};                                 \
        }                                                                       \
        _Pragma("unroll")                                                       \
        for (int q = 0; q < 3; ++q)                                             \
            if (QOK(q)) ASLOT[q] = *(const f32x4*)(APTR + rq[q] * 4);           \
        APTR += 2400;                                                           \
        __builtin_amdgcn_s_setprio(1);                                          \
        _Pragma("unroll")                                                       \
        for (int kt = 0; kt < 5; ++kt) {                                        \
            acc[0]  = __builtin_amdgcn_mfma_f32_16x16x32_bf16(afrag[0][kt],   bfr[kt],   acc[0],  0, 0, 0); \
            accB[0] = __builtin_amdgcn_mfma_f32_16x16x32_bf16(afrag[0][kt+5], bfr[kt+5], accB[0], 0, 0, 0); \
            acc[1]  = __builtin_amdgcn_mfma_f32_16x16x32_bf16(afrag[1][kt],   bfr[kt],   acc[1],  0, 0, 0); \
            accB[1] = __builtin_amdgcn_mfma_f32_16x16x32_bf16(afrag[1][kt+5], bfr[kt+5], accB[1], 0, 0, 0); \
            if (w4) {                                                           \
                acc[2]  = __builtin_amdgcn_mfma_f32_16x16x32_bf16(afrag[2][kt],   bfr[kt],   acc[2],  0, 0, 0); \
                accB[2] = __builtin_amdgcn_mfma_f32_16x16x32_bf16(afrag[2][kt+5], bfr[kt+5], accB[2], 0, 0, 0); \
            }                                                                   \
        }                                                                       \
        __builtin_amdgcn_s_setprio(0);                                          \
        _Pragma("unroll")                                                       \
        for (int q = 0; q < 3; ++q) {                                           \
            if (!QOK(q)) continue;                                              \
            f32x4 hv;                                                           \
            _Pragma("unroll")                                                   \
            for (int i = 0; i < 4; ++i) {                                       \
                float zn = acc[q][i] + accB[q][i];                              \
                float ex, sg;                                                   \
                asm("v_exp_f32 %0, %1" : "=v"(ex) : "v"(zn));                   \
                asm("v_rcp_f32 %0, %1" : "=v"(sg) : "v"(1.0f + ex));            \
                hv[i] = sg;                                                     \
            }                                                                   \
            unsigned plo, phi;                                                  \
            asm("v_cvt_pk_bf16_f32 %0, %1, %2" : "=v"(plo) : "v"(hv[0]), "v"(hv[1])); \
            asm("v_cvt_pk_bf16_f32 %0, %1, %2" : "=v"(phi) : "v"(hv[2]), "v"(hv[3])); \
            HPME[q].x = plo; HPME[q].y = phi;                                   \
            *(uint2*)((char*)hlds + ((P) ^ 1) * 10240 + ldsoff[q]) = HPME[q];   \
            if (t > 0 && rq[q] < 300)                                           \
                *(uint2*)(sbase + so + rq[q] * 2) = HPOTHER[q];                 \
        }                                                                       \
        asm volatile("s_waitcnt lgkmcnt(0)" ::: "memory");                      \
        __builtin_amdgcn_s_barrier();                                           \
        asm volatile("" ::: "memory");                                          \
    }

__global__ __launch_bounds__(512) void elman_rec_mfma(
    const float* __restrict__ W1, float* __restrict__ buf,
    float* __restrict__ hfinal)
{
    __shared__ unsigned short hlds[2][10 * 64 * 8];
    const int tid = threadIdx.x;
    const int w = tid >> 6, l = tid & 63, lg = l >> 4, ln = l & 15;
    const bool w4 = (w < 4);
    const int bb = blockIdx.x * 16 + ln;

    int rq[3], ldsoff[3];
    #pragma unroll
    for (int q = 0; q < 3; ++q) {
        int tile = w4 ? (3 * w + q) : (12 + 2 * (w - 4) + q);
        int r = tile * 16 + 4 * lg;
        rq[q] = r;
        ldsoff[q] = (((r >> 5) * 64 + ((r >> 3) & 3) * 16 + ln) * 8 + (r & 7)) * 2;
    }

    bf16x8 afrag[3][10];
    #pragma unroll
    for (int q = 0; q < 3; ++q) {
        #pragma unroll
        for (int kt = 0; kt < 10; ++kt) {
            bool qa = (q < 2) || w4;
            int tile = w4 ? (3 * w + q) : (12 + 2 * (w - 4) + q);
            int r = tile * 16 + ln;
            int k0 = kt * 32 + lg * 8;
            uint4 p = load8_cvt_s(W1 + (size_t)r * 600 + 300 + k0,
                                  qa && r < 300, 300 - k0, NL2E);
            union { uint4 u; bf16x8 s; } cv; cv.u = p;
            afrag[q][kt] = cv.s;
        }
    }

    for (int i = tid; i < 10 * 64 * 8; i += 512) hlds[0][i] = 0;

    const char* abase = (const char*)(buf + (size_t)bb * T_ * 300);
    char* sbase = (char*)buf + (size_t)bb * 16 * 76800;

    f32x4 A0[3], A1[3];
    #pragma unroll
    for (int q = 0; q < 3; ++q)
        if (QOK(q)) {
            A0[q] = *(const f32x4*)(abase + rq[q] * 4);
            A1[q] = *(const f32x4*)(abase + 1200 + rq[q] * 4);
        }
    const char* aptr0 = abase + 2400;
    const char* aptr1 = abase + 3600;
    uint2 hpA[3], hpB[3];
    __syncthreads();

    for (int t2 = 0; t2 < T_; t2 += 2) {
        K2_STEP(0, t2,     A0, aptr0, hpA, hpB)
        K2_STEP(1, t2 + 1, A1, aptr1, hpB, hpA)
    }

    {
        const int tt = T_ - 1;
        const size_t so = (size_t)(tt >> 6) * 76800 + (size_t)(tt & 63) * 600;
        #pragma unroll
        for (int q = 0; q < 3; ++q)
            if (QOK(q) && rq[q] < 300) {
                *(uint2*)(sbase + so + rq[q] * 2) = hpB[q];
                f32x4 hv;
                union { float f; unsigned u; } c0, c1, c2, c3;
                c0.u = hpB[q].x << 16; c1.u = hpB[q].x & 0xFFFF0000u;
                c2.u = hpB[q].y << 16; c3.u = hpB[q].y & 0xFFFF0000u;
                hv[0] = c0.f; hv[1] = c1.f; hv[2] = c2.f; hv[3] = c3.f;
                *(f32x4*)(hfinal + bb * 300 + rq[q]) = hv;
            }
    }
}

__global__ __launch_bounds__(256) void gemm_out(
    float* __restrict__ buf, const float* __restrict__ W2,
    const float* __restrict__ b2)
{
    __shared__ unsigned short alds[4 * 64 * 8];
    __shared__ unsigned short blds[19 * 64 * 8];
    const int tid = threadIdx.x;
    const int w = tid >> 6, l = tid & 63, lg = l >> 4, ln = l & 15;
    const size_t chunk = blockIdx.x;
    const char* pbase = (const char*)buf + chunk * 76800;

    f32x4 acc[19];
    #pragma unroll
    for (int nt = 0; nt < 19; ++nt) acc[nt] = (f32x4){0.f,0.f,0.f,0.f};

    for (int kt = 0; kt < 10; ++kt) {
        const int kc = kt * 32;
        __syncthreads();
        {
            int row = tid >> 2, kh = tid & 3;
            int k0 = kc + kh * 8;
            const char* p = pbase + row * 600;
            uint2 lo = make_uint2(0u, 0u), hi = make_uint2(0u, 0u);
            int krem = 300 - k0;
            if (krem >= 8)      { lo = *(const uint2*)(p + k0 * 2); hi = *(const uint2*)(p + k0 * 2 + 8); }
            else if (krem >= 4) { lo = *(const uint2*)(p + k0 * 2); }
            uint4 pk; pk.x = lo.x; pk.y = lo.y; pk.z = hi.x; pk.w = hi.y;
            *(uint4*)&alds[(((row >> 4) * 64) + kh * 16 + (row & 15)) * 8] = pk;
        }
        #pragma unroll
        for (int rep = 0; rep < 5; ++rep) {
            int e = tid + rep * 256;
            if (e < 1216) {
                int nn = e >> 2, kh = e & 3;
                int k0 = kc + kh * 8;
                uint4 p = load8_cvt(W2 + (size_t)nn * 300 + k0, nn < 300, 300 - k0);
                *(uint4*)&blds[(((nn >> 4) * 64) + kh * 16 + (nn & 15)) * 8] = p;
            }
        }
        __syncthreads();
        bf16x8 afr = *(const bf16x8*)&alds[(w * 64 + l) * 8];
        #pragma unroll
        for (int nt = 0; nt < 19; ++nt) {
            bf16x8 bfr = *(const bf16x8*)&blds[(nt * 64 + l) * 8];
            acc[nt] = __builtin_amdgcn_mfma_f32_16x16x32_bf16(afr, bfr, acc[nt], 0, 0, 0);
        }
    }

    float* frow = buf + chunk * 19200;
    #pragma unroll
    for (int nt = 0; nt < 19; ++nt) {
        int n = nt * 16 + ln;
        if (n < 300) {
            float bias = b2[n];
            int mr = w * 16 + lg * 4;
            #pragma unroll
            for (int i = 0; i < 4; ++i)
                frow[(mr + i) * 300 + n] = acc[nt][i] + bias;
        }
    }
}

// ---------------------------------------------------------------------------
extern "C" void kernel_launch(void* const* d_in, const int* in_sizes, int n_in,
                              void* d_out, int out_size, void* d_ws, size_t ws_size,
                              hipStream_t stream)
{
    const float* x  = (const float*)d_in[0];
    const float* W1 = (const float*)d_in[1];
    const float* b1 = (const float*)d_in[2];
    const float* W2 = (const float*)d_in[3];
    const float* b2 = (const float*)d_in[4];

    float* out    = (float*)d_out;
    float* hfinal = out + (size_t)HB;

    const size_t HT4 = (size_t)T_ * 75 * 128 * 8;   // 78,643,200 B
    if (ws_size >= HT4 + 2 * 76800) {               // + prefetch overrun slack
        gemm_in_t2<<<512, 512, 0, stream>>>(x, W1, b1, (char*)d_ws);
        elman_rec_ws<<<8, 512, 0, stream>>>(W1, hfinal, (char*)d_ws);
        gemm_out_t2<<<512, 512, 0, stream>>>((const char*)d_ws, W2, b2, out);
    } else {
        gemm_in<<<dim3(1024, 2), 256, 0, stream>>>(x, W1, b1, out);
        elman_rec_mfma<<<8, 512, 0, stream>>>(W1, out, hfinal);
        gemm_out<<<2048, 256, 0, stream>>>(out, W2, b2);
    }
}